// Round 5
// baseline (3679.718 us; speedup 1.0000x reference)
//
#include <hip/hip_runtime.h>
#include <hip/hip_bf16.h>
#include <cstdint>

// ---------------------------------------------------------------------------
// Binarized CNN. Numerics analysis:
//  - binarize(x) = fl(x + fl(sign(x)-x)) == exactly sign(x) for |x| <= ~2
//    (Sterbenz for x in [0.5,2]; rounding error < half-ulp(1) below 0.5).
//  - Hence layers 2-4 are EXACT small-integer arithmetic (sums <= 72,
//    exact in f32 regardless of order/backend). Only conv1's f32 summation
//    order matters: its sign feeds binarize and cascades.
//  - Reference is precomputed by driver-side JAX on CPU -> XLA CPU -> Eigen
//    conv: k-reduction sequential in k = ((ky*3+kx)*3+ic), i.e. (ky,kx,ic)
//    with ic innermost, single accumulator. k1 replicates that exactly.
// ---------------------------------------------------------------------------

#define WOFF_W1S 0          // float[216]
#define WOFF_WS2 2048       // int8[16*8*9]
#define WOFF_WS3 4096       // int8[32*16*9]
#define WOFF_WS4 8704       // int8[2*32*9]
#define WEIGHTS_BYTES 16384

#define A1_PB (8*256*256)       // int8 bytes per batch
#define A2_PB (16*254*254)
#define A3_PB (32*252*252)

__device__ __forceinline__ int fsign(float w) {
    return (w > 0.f) ? 1 : ((w < 0.f) ? -1 : 0);
}

// ---- weight prep: plain int8 signs (OIHW), f32 signs for conv1 -----------
__global__ __launch_bounds__(256) void kprep(const float* __restrict__ w1,
                                             const float* __restrict__ w2,
                                             const float* __restrict__ w3,
                                             const float* __restrict__ w4,
                                             float* __restrict__ w1s,
                                             signed char* __restrict__ ws2,
                                             signed char* __restrict__ ws3,
                                             signed char* __restrict__ ws4) {
    int t = threadIdx.x;
    for (int i = t; i < 216; i += 256) {
        float w = w1[i];
        w1s[i] = (w > 0.f) ? 1.f : ((w < 0.f) ? -1.f : 0.f);
    }
    for (int i = t; i < 16 * 8 * 9; i += 256)  ws2[i] = (signed char)fsign(w2[i]);
    for (int i = t; i < 32 * 16 * 9; i += 256) ws3[i] = (signed char)fsign(w3[i]);
    for (int i = t; i < 2 * 32 * 9; i += 256)  ws4[i] = (signed char)fsign(w4[i]);
}

// ---- layer 1: pad(1)+conv(3->8)+hardtanh+maxpool2+sign -------------------
// f32, per-accumulator addition order strictly k-ascending with
// k = (ky*3 + kx)*3 + ic   (Eigen/XLA-CPU NHWC-HWIO im2col order).
__global__ __launch_bounds__(256) void k1(const float* __restrict__ x,
                                          const float* __restrict__ w1s,
                                          signed char* __restrict__ a1, int n0) {
    int ox = threadIdx.x;   // 0..255
    int oy = blockIdx.y;    // 0..255
    int ln = blockIdx.z;
    const float* xn = x + (size_t)(n0 + ln) * 3 * 512 * 512;

    // 4x4 input patch per ic (covers the 2x2 conv positions of this pool cell)
    float v[3][16];
    int iy0 = 2 * oy - 1, ix0 = 2 * ox - 1;
    for (int ic = 0; ic < 3; ++ic) {
        const float* xc = xn + (size_t)ic * 512 * 512;
#pragma unroll
        for (int r = 0; r < 4; ++r) {
            int iy = iy0 + r;
            bool yok = ((unsigned)iy < 512u);
#pragma unroll
            for (int c = 0; c < 4; ++c) {
                int ix = ix0 + c;
                v[ic][r * 4 + c] = (yok && ((unsigned)ix < 512u))
                                       ? xc[(size_t)iy * 512 + ix] : 1.0f;
            }
        }
    }

    float acc[4][8];
#pragma unroll
    for (int p = 0; p < 4; ++p)
#pragma unroll
        for (int o = 0; o < 8; ++o) acc[p][o] = 0.f;

    // k-ascending: ky outer, kx mid, ic inner — each acc[p][o] is a single
    // sequential f32 accumulation chain in exactly this order.
#pragma unroll
    for (int ky = 0; ky < 3; ++ky) {
#pragma unroll
        for (int kx = 0; kx < 3; ++kx) {
#pragma unroll
            for (int ic = 0; ic < 3; ++ic) {
                float v00 = v[ic][(ky + 0) * 4 + (kx + 0)];
                float v01 = v[ic][(ky + 0) * 4 + (kx + 1)];
                float v10 = v[ic][(ky + 1) * 4 + (kx + 0)];
                float v11 = v[ic][(ky + 1) * 4 + (kx + 1)];
#pragma unroll
                for (int o = 0; o < 8; ++o) {
                    float w = w1s[o * 27 + ic * 9 + ky * 3 + kx];
                    acc[0][o] += w * v00;
                    acc[1][o] += w * v01;
                    acc[2][o] += w * v10;
                    acc[3][o] += w * v11;
                }
            }
        }
    }

#pragma unroll
    for (int o = 0; o < 8; ++o) {
        float m = fmaxf(fmaxf(acc[0][o], acc[1][o]), fmaxf(acc[2][o], acc[3][o]));
        int sg = (m > 0.f) ? 1 : ((m < 0.f) ? -1 : 0);
        a1[(((size_t)ln * 8 + o) * 256 + oy) * 256 + ox] = (signed char)sg;
    }
}

// ---- layer 2: conv(8->16), exact int --------------------------------------
__global__ __launch_bounds__(256) void k2(const signed char* __restrict__ a1,
                                          const signed char* __restrict__ ws2,
                                          signed char* __restrict__ a2) {
    int ox = threadIdx.x; if (ox >= 254) return;
    int oy = blockIdx.y;
    int z = blockIdx.z;                // ln*16 + oc
    int ln = z >> 4, oc = z & 15;

    int acc = 0;
    for (int ic = 0; ic < 8; ++ic) {
        for (int ky = 0; ky < 3; ++ky) {
            const signed char* row = a1 + (((size_t)ln * 8 + ic) * 256 + (oy + ky)) * 256 + ox;
            const signed char* wb  = ws2 + (oc * 8 + ic) * 9 + ky * 3;
            acc += (int)row[0] * (int)wb[0];
            acc += (int)row[1] * (int)wb[1];
            acc += (int)row[2] * (int)wb[2];
        }
    }
    int r = min(max(acc, -1), 1);
    a2[(((size_t)ln * 16 + oc) * 254 + oy) * 254 + ox] = (signed char)r;
}

// ---- layer 3: conv(16->32), exact int -------------------------------------
__global__ __launch_bounds__(256) void k3(const signed char* __restrict__ a2,
                                          const signed char* __restrict__ ws3,
                                          signed char* __restrict__ a3) {
    int ox = threadIdx.x; if (ox >= 252) return;
    int oy = blockIdx.y;
    int z = blockIdx.z;                // ln*32 + oc
    int ln = z >> 5, oc = z & 31;

    int acc = 0;
    for (int ic = 0; ic < 16; ++ic) {
        for (int ky = 0; ky < 3; ++ky) {
            const signed char* row = a2 + (((size_t)ln * 16 + ic) * 254 + (oy + ky)) * 254 + ox;
            const signed char* wb  = ws3 + (oc * 16 + ic) * 9 + ky * 3;
            acc += (int)row[0] * (int)wb[0];
            acc += (int)row[1] * (int)wb[1];
            acc += (int)row[2] * (int)wb[2];
        }
    }
    int r = min(max(acc, -1), 1);
    a3[(((size_t)ln * 32 + oc) * 252 + oy) * 252 + ox] = (signed char)r;
}

// ---- layer 4: conv(32->2), exact int, float out ----------------------------
__global__ __launch_bounds__(256) void k4(const signed char* __restrict__ a3,
                                          const signed char* __restrict__ ws4,
                                          float* __restrict__ out, int n0) {
    int ox = threadIdx.x; if (ox >= 250) return;
    int oy = blockIdx.y;
    int ln = blockIdx.z;

    int acc0 = 0, acc1 = 0;
    for (int ic = 0; ic < 32; ++ic) {
        for (int ky = 0; ky < 3; ++ky) {
            const signed char* row = a3 + (((size_t)ln * 32 + ic) * 252 + (oy + ky)) * 252 + ox;
            const signed char* w0  = ws4 + (0 * 32 + ic) * 9 + ky * 3;
            const signed char* w1  = ws4 + (1 * 32 + ic) * 9 + ky * 3;
            int v0 = row[0], v1 = row[1], v2 = row[2];
            acc0 += v0 * (int)w0[0] + v1 * (int)w0[1] + v2 * (int)w0[2];
            acc1 += v0 * (int)w1[0] + v1 * (int)w1[1] + v2 * (int)w1[2];
        }
    }
    size_t gn = (size_t)(n0 + ln);
    out[((gn * 2 + 0) * 250 + oy) * 250 + ox] = fminf(fmaxf((float)acc0, -1.f), 1.f);
    out[((gn * 2 + 1) * 250 + oy) * 250 + ox] = fminf(fmaxf((float)acc1, -1.f), 1.f);
}

extern "C" void kernel_launch(void* const* d_in, const int* in_sizes, int n_in,
                              void* d_out, int out_size, void* d_ws, size_t ws_size,
                              hipStream_t stream) {
    const float* x  = (const float*)d_in[0];
    const float* w1 = (const float*)d_in[1];
    const float* w2 = (const float*)d_in[2];
    const float* w3 = (const float*)d_in[3];
    const float* w4 = (const float*)d_in[4];
    char* ws = (char*)d_ws;

    float*       w1s = (float*)(ws + WOFF_W1S);
    signed char* ws2 = (signed char*)(ws + WOFF_WS2);
    signed char* ws3 = (signed char*)(ws + WOFF_WS3);
    signed char* ws4 = (signed char*)(ws + WOFF_WS4);
    float*       out = (float*)d_out;

    // pick largest batch-chunk NC (power of 2, divides 32) that fits ws
    size_t per = (size_t)A1_PB + (size_t)A2_PB + (size_t)A3_PB;
    int NC = 32;
    while (NC > 1 && (size_t)WEIGHTS_BYTES + (size_t)NC * per > ws_size) NC >>= 1;

    signed char* A1 = (signed char*)(ws + WEIGHTS_BYTES);
    signed char* A2 = A1 + (size_t)NC * A1_PB;
    signed char* A3 = A2 + (size_t)NC * A2_PB;

    kprep<<<1, 256, 0, stream>>>(w1, w2, w3, w4, w1s, ws2, ws3, ws4);
    for (int n0 = 0; n0 < 32; n0 += NC) {
        k1<<<dim3(1, 256, NC),      256, 0, stream>>>(x, w1s, A1, n0);
        k2<<<dim3(1, 254, NC * 16), 256, 0, stream>>>(A1, ws2, A2);
        k3<<<dim3(1, 252, NC * 32), 256, 0, stream>>>(A2, ws3, A3);
        k4<<<dim3(1, 250, NC),      256, 0, stream>>>(A3, ws4, out, n0);
    }
}

// Round 6
// 229.065 us; speedup vs baseline: 16.0641x; 16.0641x over previous
//
#include <hip/hip_runtime.h>
#include <hip/hip_bf16.h>
#include <cstdint>

// ---------------------------------------------------------------------------
// Binarized CNN. Verified numerics (R5 passed bit-exact):
//  - binarize(x) == sign(x) exactly; layers 2-4 are exact small-int math in
//    any order -> safe to pack 4 int8 channels/dword and use v_dot4_i32_i8.
//  - conv1 MUST keep f32 accumulation in k-ascending order
//    k = (ky*3+kx)*3+ic (Eigen/XLA-CPU im2col) — k1 below is bit-identical
//    to the R5-passing version, only its output is packed into dwords.
// ---------------------------------------------------------------------------

#define WOFF_W2P 0          // int32[16*2*9]
#define WOFF_W3P 8192       // int32[32*4*9]
#define WOFF_W4P 16384      // int32[2*8*9]
#define WOFF_W1S 20480      // float[216]
#define WEIGHTS_BYTES 32768

#define A1_PB (2*256*256*4)     // bytes per batch (packed u32)
#define A2_PB (4*254*254*4)
#define A3_PB (8*252*252*4)

__device__ __forceinline__ int dot4(int a, int b, int c) {
#if __has_builtin(__builtin_amdgcn_sdot4)
    return __builtin_amdgcn_sdot4(a, b, c, false);
#else
    int s = c;
#pragma unroll
    for (int j = 0; j < 4; ++j) {
        int av = (a << (24 - 8 * j)) >> 24;
        int bv = (b << (24 - 8 * j)) >> 24;
        s += av * bv;
    }
    return s;
#endif
}

__device__ __forceinline__ int fsign(float w) {
    return (w > 0.f) ? 1 : ((w < 0.f) ? -1 : 0);
}

// ---- weight prep: pack signs into dot4-ready dwords ----------------------
__global__ __launch_bounds__(256) void kprep(const float* __restrict__ w1,
                                             const float* __restrict__ w2,
                                             const float* __restrict__ w3,
                                             const float* __restrict__ w4,
                                             int* __restrict__ w2p,
                                             int* __restrict__ w3p,
                                             int* __restrict__ w4p,
                                             float* __restrict__ w1s) {
    int t = threadIdx.x;
    // w2p[(oc*2+icg)*9 + k] byte j = sign(w2[(oc*8 + icg*4 + j)*9 + k])
    for (int idx = t; idx < 16 * 2 * 9; idx += 256) {
        int k = idx % 9, icg = (idx / 9) % 2, oc = idx / 18;
        int pack = 0;
#pragma unroll
        for (int j = 0; j < 4; ++j)
            pack |= (fsign(w2[(oc * 8 + icg * 4 + j) * 9 + k]) & 0xff) << (8 * j);
        w2p[idx] = pack;
    }
    // w3p[(oc*4+icg)*9 + k] byte j = sign(w3[(oc*16 + icg*4 + j)*9 + k])
    for (int idx = t; idx < 32 * 4 * 9; idx += 256) {
        int k = idx % 9, icg = (idx / 9) % 4, oc = idx / 36;
        int pack = 0;
#pragma unroll
        for (int j = 0; j < 4; ++j)
            pack |= (fsign(w3[(oc * 16 + icg * 4 + j) * 9 + k]) & 0xff) << (8 * j);
        w3p[idx] = pack;
    }
    // w4p[(oc*8+icg)*9 + k] byte j = sign(w4[(oc*32 + icg*4 + j)*9 + k])
    for (int idx = t; idx < 2 * 8 * 9; idx += 256) {
        int k = idx % 9, icg = (idx / 9) % 8, oc = idx / 72;
        int pack = 0;
#pragma unroll
        for (int j = 0; j < 4; ++j)
            pack |= (fsign(w4[(oc * 32 + icg * 4 + j) * 9 + k]) & 0xff) << (8 * j);
        w4p[idx] = pack;
    }
    for (int i = t; i < 216; i += 256) {
        float w = w1[i];
        w1s[i] = (w > 0.f) ? 1.f : ((w < 0.f) ? -1.f : 0.f);
    }
}

// ---- layer 1: pad(1)+conv(3->8)+hardtanh+maxpool2+sign, packed out -------
// Bit-identical accumulation to the R5-passing kernel: per-acc chain order
// strictly (ky, kx, ic)-ascending, f32, mul+add.
__global__ __launch_bounds__(256) void k1(const float* __restrict__ x,
                                          const float* __restrict__ w1s,
                                          uint32_t* __restrict__ a1, int n0) {
    int ox = threadIdx.x;   // 0..255
    int oy = blockIdx.y;    // 0..255
    int ln = blockIdx.z;
    const float* xn = x + (size_t)(n0 + ln) * 3 * 512 * 512;

    float v[3][16];
    int iy0 = 2 * oy - 1, ix0 = 2 * ox - 1;
    for (int ic = 0; ic < 3; ++ic) {
        const float* xc = xn + (size_t)ic * 512 * 512;
#pragma unroll
        for (int r = 0; r < 4; ++r) {
            int iy = iy0 + r;
            bool yok = ((unsigned)iy < 512u);
#pragma unroll
            for (int c = 0; c < 4; ++c) {
                int ix = ix0 + c;
                v[ic][r * 4 + c] = (yok && ((unsigned)ix < 512u))
                                       ? xc[(size_t)iy * 512 + ix] : 1.0f;
            }
        }
    }

    float acc[4][8];
#pragma unroll
    for (int p = 0; p < 4; ++p)
#pragma unroll
        for (int o = 0; o < 8; ++o) acc[p][o] = 0.f;

#pragma unroll
    for (int ky = 0; ky < 3; ++ky) {
#pragma unroll
        for (int kx = 0; kx < 3; ++kx) {
#pragma unroll
            for (int ic = 0; ic < 3; ++ic) {
                float v00 = v[ic][(ky + 0) * 4 + (kx + 0)];
                float v01 = v[ic][(ky + 0) * 4 + (kx + 1)];
                float v10 = v[ic][(ky + 1) * 4 + (kx + 0)];
                float v11 = v[ic][(ky + 1) * 4 + (kx + 1)];
#pragma unroll
                for (int o = 0; o < 8; ++o) {
                    float w = w1s[o * 27 + ic * 9 + ky * 3 + kx];
                    acc[0][o] += w * v00;
                    acc[1][o] += w * v01;
                    acc[2][o] += w * v10;
                    acc[3][o] += w * v11;
                }
            }
        }
    }

    uint32_t d0 = 0, d1 = 0;
#pragma unroll
    for (int o = 0; o < 8; ++o) {
        float m = fmaxf(fmaxf(acc[0][o], acc[1][o]), fmaxf(acc[2][o], acc[3][o]));
        int sg = (m > 0.f) ? 1 : ((m < 0.f) ? -1 : 0);
        if (o < 4) d0 |= (uint32_t)(sg & 0xff) << (8 * o);
        else       d1 |= (uint32_t)(sg & 0xff) << (8 * (o - 4));
    }
    size_t base = (((size_t)ln * 2) * 256 + oy) * 256 + ox;
    a1[base]             = d0;
    a1[base + 256 * 256] = d1;
}

// ---- layer 2: conv(8->16) ternary, dot4 ----------------------------------
__global__ __launch_bounds__(256) void k2(const uint32_t* __restrict__ a1,
                                          const int* __restrict__ w2p,
                                          uint32_t* __restrict__ a2) {
    int ox = threadIdx.x; if (ox >= 254) return;
    int oy = blockIdx.y;            // 0..253
    int z = blockIdx.z;             // ln*4 + ocg
    int ln = z >> 2, ocg = z & 3;

    int acc[4] = {0, 0, 0, 0};
#pragma unroll
    for (int icg = 0; icg < 2; ++icg) {
#pragma unroll
        for (int ky = 0; ky < 3; ++ky) {
            const uint32_t* row = a1 + (((size_t)ln * 2 + icg) * 256 + (oy + ky)) * 256 + ox;
            int v0 = (int)row[0], v1 = (int)row[1], v2 = (int)row[2];
#pragma unroll
            for (int o = 0; o < 4; ++o) {
                const int* wb = w2p + (((ocg * 4 + o) * 2 + icg) * 9) + ky * 3;
                acc[o] = dot4(v0, wb[0], acc[o]);
                acc[o] = dot4(v1, wb[1], acc[o]);
                acc[o] = dot4(v2, wb[2], acc[o]);
            }
        }
    }
    uint32_t pack = 0;
#pragma unroll
    for (int o = 0; o < 4; ++o) {
        int r = min(max(acc[o], -1), 1);
        pack |= (uint32_t)(r & 0xff) << (8 * o);
    }
    a2[(((size_t)ln * 4 + ocg) * 254 + oy) * 254 + ox] = pack;
}

// ---- layer 3: conv(16->32) ternary, dot4 ---------------------------------
__global__ __launch_bounds__(256) void k3(const uint32_t* __restrict__ a2,
                                          const int* __restrict__ w3p,
                                          uint32_t* __restrict__ a3) {
    int ox = threadIdx.x; if (ox >= 252) return;
    int oy = blockIdx.y;            // 0..251
    int z = blockIdx.z;             // ln*8 + ocg
    int ln = z >> 3, ocg = z & 7;

    int acc[4] = {0, 0, 0, 0};
#pragma unroll
    for (int icg = 0; icg < 4; ++icg) {
#pragma unroll
        for (int ky = 0; ky < 3; ++ky) {
            const uint32_t* row = a2 + (((size_t)ln * 4 + icg) * 254 + (oy + ky)) * 254 + ox;
            int v0 = (int)row[0], v1 = (int)row[1], v2 = (int)row[2];
#pragma unroll
            for (int o = 0; o < 4; ++o) {
                const int* wb = w3p + (((ocg * 4 + o) * 4 + icg) * 9) + ky * 3;
                acc[o] = dot4(v0, wb[0], acc[o]);
                acc[o] = dot4(v1, wb[1], acc[o]);
                acc[o] = dot4(v2, wb[2], acc[o]);
            }
        }
    }
    uint32_t pack = 0;
#pragma unroll
    for (int o = 0; o < 4; ++o) {
        int r = min(max(acc[o], -1), 1);
        pack |= (uint32_t)(r & 0xff) << (8 * o);
    }
    a3[(((size_t)ln * 8 + ocg) * 252 + oy) * 252 + ox] = pack;
}

// ---- layer 4: conv(32->2) ternary, dot4, float out -----------------------
__global__ __launch_bounds__(256) void k4(const uint32_t* __restrict__ a3,
                                          const int* __restrict__ w4p,
                                          float* __restrict__ out, int n0) {
    int ox = threadIdx.x; if (ox >= 250) return;
    int oy = blockIdx.y;            // 0..249
    int ln = blockIdx.z;

    int acc[2] = {0, 0};
#pragma unroll
    for (int icg = 0; icg < 8; ++icg) {
#pragma unroll
        for (int ky = 0; ky < 3; ++ky) {
            const uint32_t* row = a3 + (((size_t)ln * 8 + icg) * 252 + (oy + ky)) * 252 + ox;
            int v0 = (int)row[0], v1 = (int)row[1], v2 = (int)row[2];
#pragma unroll
            for (int o = 0; o < 2; ++o) {
                const int* wb = w4p + ((o * 8 + icg) * 9) + ky * 3;
                acc[o] = dot4(v0, wb[0], acc[o]);
                acc[o] = dot4(v1, wb[1], acc[o]);
                acc[o] = dot4(v2, wb[2], acc[o]);
            }
        }
    }
    size_t gn = (size_t)(n0 + ln);
#pragma unroll
    for (int o = 0; o < 2; ++o) {
        float v = fminf(fmaxf((float)acc[o], -1.f), 1.f);
        out[((gn * 2 + o) * 250 + oy) * 250 + ox] = v;
    }
}

extern "C" void kernel_launch(void* const* d_in, const int* in_sizes, int n_in,
                              void* d_out, int out_size, void* d_ws, size_t ws_size,
                              hipStream_t stream) {
    const float* x  = (const float*)d_in[0];
    const float* w1 = (const float*)d_in[1];
    const float* w2 = (const float*)d_in[2];
    const float* w3 = (const float*)d_in[3];
    const float* w4 = (const float*)d_in[4];
    char* ws = (char*)d_ws;

    int*   w2p = (int*)(ws + WOFF_W2P);
    int*   w3p = (int*)(ws + WOFF_W3P);
    int*   w4p = (int*)(ws + WOFF_W4P);
    float* w1s = (float*)(ws + WOFF_W1S);
    float* out = (float*)d_out;

    // pick largest batch-chunk NC (power of 2, divides 32) that fits ws
    size_t per = (size_t)A1_PB + (size_t)A2_PB + (size_t)A3_PB;
    int NC = 32;
    while (NC > 1 && (size_t)WEIGHTS_BYTES + (size_t)NC * per > ws_size) NC >>= 1;

    uint32_t* A1 = (uint32_t*)(ws + WEIGHTS_BYTES);
    uint32_t* A2 = (uint32_t*)(ws + WEIGHTS_BYTES + (size_t)NC * A1_PB);
    uint32_t* A3 = (uint32_t*)(ws + WEIGHTS_BYTES + (size_t)NC * (A1_PB + A2_PB));

    kprep<<<1, 256, 0, stream>>>(w1, w2, w3, w4, w2p, w3p, w4p, w1s);
    for (int n0 = 0; n0 < 32; n0 += NC) {
        k1<<<dim3(1, 256, NC),     256, 0, stream>>>(x, w1s, A1, n0);
        k2<<<dim3(1, 254, NC * 4), 256, 0, stream>>>(A1, w2p, A2);
        k3<<<dim3(1, 252, NC * 8), 256, 0, stream>>>(A2, w3p, A3);
        k4<<<dim3(1, 250, NC),     256, 0, stream>>>(A3, w4p, out, n0);
    }
}

// Round 7
// 197.735 us; speedup vs baseline: 18.6094x; 1.1584x over previous
//
#include <hip/hip_runtime.h>
#include <hip/hip_bf16.h>
#include <cstdint>

// ---------------------------------------------------------------------------
// Binarized CNN. Verified numerics (R5/R6 passed bit-exact):
//  - binarize(x) == sign(x) exactly; layers 2-4 are exact small-int math in
//    any order -> packed 4 int8 channels/dword + v_dot4_i32_i8, any order.
//  - conv1 MUST keep f32 accumulation in k-ascending order
//    k = (ky*3+kx)*3+ic (Eigen/XLA-CPU im2col) — k1 is bit-identical to the
//    passing version. DO NOT REORDER k1's accumulation.
//  - R7: row-blocking in k2/k3/k4 (2/4/2 output rows per thread) to amortize
//    loads, addressing and weight reuse over multiple pixels.
// ---------------------------------------------------------------------------

#define WOFF_W2P 0          // int32[16*2*9]
#define WOFF_W3P 8192       // int32[32*4*9]
#define WOFF_W4P 16384      // int32[2*8*9]
#define WOFF_W1S 20480      // float[216]
#define WEIGHTS_BYTES 32768

#define A1_PB (2*256*256*4)     // bytes per batch (packed u32)
#define A2_PB (4*254*254*4)
#define A3_PB (8*252*252*4)

__device__ __forceinline__ int dot4(int a, int b, int c) {
#if __has_builtin(__builtin_amdgcn_sdot4)
    return __builtin_amdgcn_sdot4(a, b, c, false);
#else
    int s = c;
#pragma unroll
    for (int j = 0; j < 4; ++j) {
        int av = (a << (24 - 8 * j)) >> 24;
        int bv = (b << (24 - 8 * j)) >> 24;
        s += av * bv;
    }
    return s;
#endif
}

__device__ __forceinline__ int fsign(float w) {
    return (w > 0.f) ? 1 : ((w < 0.f) ? -1 : 0);
}

// ---- weight prep: pack signs into dot4-ready dwords ----------------------
__global__ __launch_bounds__(256) void kprep(const float* __restrict__ w1,
                                             const float* __restrict__ w2,
                                             const float* __restrict__ w3,
                                             const float* __restrict__ w4,
                                             int* __restrict__ w2p,
                                             int* __restrict__ w3p,
                                             int* __restrict__ w4p,
                                             float* __restrict__ w1s) {
    int t = threadIdx.x;
    for (int idx = t; idx < 16 * 2 * 9; idx += 256) {
        int k = idx % 9, icg = (idx / 9) % 2, oc = idx / 18;
        int pack = 0;
#pragma unroll
        for (int j = 0; j < 4; ++j)
            pack |= (fsign(w2[(oc * 8 + icg * 4 + j) * 9 + k]) & 0xff) << (8 * j);
        w2p[idx] = pack;
    }
    for (int idx = t; idx < 32 * 4 * 9; idx += 256) {
        int k = idx % 9, icg = (idx / 9) % 4, oc = idx / 36;
        int pack = 0;
#pragma unroll
        for (int j = 0; j < 4; ++j)
            pack |= (fsign(w3[(oc * 16 + icg * 4 + j) * 9 + k]) & 0xff) << (8 * j);
        w3p[idx] = pack;
    }
    for (int idx = t; idx < 2 * 8 * 9; idx += 256) {
        int k = idx % 9, icg = (idx / 9) % 8, oc = idx / 72;
        int pack = 0;
#pragma unroll
        for (int j = 0; j < 4; ++j)
            pack |= (fsign(w4[(oc * 32 + icg * 4 + j) * 9 + k]) & 0xff) << (8 * j);
        w4p[idx] = pack;
    }
    for (int i = t; i < 216; i += 256) {
        float w = w1[i];
        w1s[i] = (w > 0.f) ? 1.f : ((w < 0.f) ? -1.f : 0.f);
    }
}

// ---- layer 1: pad(1)+conv(3->8)+hardtanh+maxpool2+sign, packed out -------
// BIT-IDENTICAL accumulation to the passing kernel: (ky,kx,ic)-ascending f32.
__global__ __launch_bounds__(256) void k1(const float* __restrict__ x,
                                          const float* __restrict__ w1s,
                                          uint32_t* __restrict__ a1, int n0) {
    int ox = threadIdx.x;   // 0..255
    int oy = blockIdx.y;    // 0..255
    int ln = blockIdx.z;
    const float* xn = x + (size_t)(n0 + ln) * 3 * 512 * 512;

    float v[3][16];
    int iy0 = 2 * oy - 1, ix0 = 2 * ox - 1;
    for (int ic = 0; ic < 3; ++ic) {
        const float* xc = xn + (size_t)ic * 512 * 512;
#pragma unroll
        for (int r = 0; r < 4; ++r) {
            int iy = iy0 + r;
            bool yok = ((unsigned)iy < 512u);
#pragma unroll
            for (int c = 0; c < 4; ++c) {
                int ix = ix0 + c;
                v[ic][r * 4 + c] = (yok && ((unsigned)ix < 512u))
                                       ? xc[(size_t)iy * 512 + ix] : 1.0f;
            }
        }
    }

    float acc[4][8];
#pragma unroll
    for (int p = 0; p < 4; ++p)
#pragma unroll
        for (int o = 0; o < 8; ++o) acc[p][o] = 0.f;

#pragma unroll
    for (int ky = 0; ky < 3; ++ky) {
#pragma unroll
        for (int kx = 0; kx < 3; ++kx) {
#pragma unroll
            for (int ic = 0; ic < 3; ++ic) {
                float v00 = v[ic][(ky + 0) * 4 + (kx + 0)];
                float v01 = v[ic][(ky + 0) * 4 + (kx + 1)];
                float v10 = v[ic][(ky + 1) * 4 + (kx + 0)];
                float v11 = v[ic][(ky + 1) * 4 + (kx + 1)];
#pragma unroll
                for (int o = 0; o < 8; ++o) {
                    float w = w1s[o * 27 + ic * 9 + ky * 3 + kx];
                    acc[0][o] += w * v00;
                    acc[1][o] += w * v01;
                    acc[2][o] += w * v10;
                    acc[3][o] += w * v11;
                }
            }
        }
    }

    uint32_t d0 = 0, d1 = 0;
#pragma unroll
    for (int o = 0; o < 8; ++o) {
        float m = fmaxf(fmaxf(acc[0][o], acc[1][o]), fmaxf(acc[2][o], acc[3][o]));
        int sg = (m > 0.f) ? 1 : ((m < 0.f) ? -1 : 0);
        if (o < 4) d0 |= (uint32_t)(sg & 0xff) << (8 * o);
        else       d1 |= (uint32_t)(sg & 0xff) << (8 * (o - 4));
    }
    size_t base = (((size_t)ln * 2) * 256 + oy) * 256 + ox;
    a1[base]             = d0;
    a1[base + 256 * 256] = d1;
}

// ---- layer 2: conv(8->16) ternary, dot4, 2 output rows/thread ------------
__global__ __launch_bounds__(256) void k2(const uint32_t* __restrict__ a1,
                                          const int* __restrict__ w2p,
                                          uint32_t* __restrict__ a2) {
    int ox = threadIdx.x; if (ox >= 254) return;
    int oy0 = blockIdx.y * 2;       // 0..252, 127 tiles
    int z = blockIdx.z;             // ln*4 + ocg
    int ln = z >> 2, ocg = z & 3;

    int acc[2][4];
#pragma unroll
    for (int p = 0; p < 2; ++p)
#pragma unroll
        for (int o = 0; o < 4; ++o) acc[p][o] = 0;

#pragma unroll
    for (int icg = 0; icg < 2; ++icg) {
        uint32_t r[4][3];
        const uint32_t* base = a1 + (((size_t)ln * 2 + icg) * 256 + oy0) * 256 + ox;
#pragma unroll
        for (int j = 0; j < 4; ++j)
#pragma unroll
            for (int c = 0; c < 3; ++c) r[j][c] = base[j * 256 + c];

#pragma unroll
        for (int o = 0; o < 4; ++o) {
            const int* wb = w2p + (((ocg * 4 + o) * 2 + icg) * 9);
#pragma unroll
            for (int ky = 0; ky < 3; ++ky) {
#pragma unroll
                for (int p = 0; p < 2; ++p) {
                    acc[p][o] = dot4((int)r[p + ky][0], wb[ky * 3 + 0], acc[p][o]);
                    acc[p][o] = dot4((int)r[p + ky][1], wb[ky * 3 + 1], acc[p][o]);
                    acc[p][o] = dot4((int)r[p + ky][2], wb[ky * 3 + 2], acc[p][o]);
                }
            }
        }
    }
#pragma unroll
    for (int p = 0; p < 2; ++p) {
        uint32_t pack = 0;
#pragma unroll
        for (int o = 0; o < 4; ++o) {
            int rc = min(max(acc[p][o], -1), 1);
            pack |= (uint32_t)(rc & 0xff) << (8 * o);
        }
        a2[(((size_t)ln * 4 + ocg) * 254 + (oy0 + p)) * 254 + ox] = pack;
    }
}

// ---- layer 3: conv(16->32) ternary, dot4, 4 output rows/thread -----------
__global__ __launch_bounds__(256) void k3(const uint32_t* __restrict__ a2,
                                          const int* __restrict__ w3p,
                                          uint32_t* __restrict__ a3) {
    int ox = threadIdx.x; if (ox >= 252) return;
    int oy0 = blockIdx.y * 4;       // 0..248, 63 tiles
    int z = blockIdx.z;             // ln*8 + ocg
    int ln = z >> 3, ocg = z & 7;

    int acc[4][4];
#pragma unroll
    for (int p = 0; p < 4; ++p)
#pragma unroll
        for (int o = 0; o < 4; ++o) acc[p][o] = 0;

#pragma unroll
    for (int icg = 0; icg < 4; ++icg) {
        uint32_t r[6][3];
        const uint32_t* base = a2 + (((size_t)ln * 4 + icg) * 254 + oy0) * 254 + ox;
#pragma unroll
        for (int j = 0; j < 6; ++j)
#pragma unroll
            for (int c = 0; c < 3; ++c) r[j][c] = base[j * 254 + c];

#pragma unroll
        for (int o = 0; o < 4; ++o) {
            const int* wb = w3p + (((ocg * 4 + o) * 4 + icg) * 9);
#pragma unroll
            for (int ky = 0; ky < 3; ++ky) {
#pragma unroll
                for (int p = 0; p < 4; ++p) {
                    acc[p][o] = dot4((int)r[p + ky][0], wb[ky * 3 + 0], acc[p][o]);
                    acc[p][o] = dot4((int)r[p + ky][1], wb[ky * 3 + 1], acc[p][o]);
                    acc[p][o] = dot4((int)r[p + ky][2], wb[ky * 3 + 2], acc[p][o]);
                }
            }
        }
    }
#pragma unroll
    for (int p = 0; p < 4; ++p) {
        uint32_t pack = 0;
#pragma unroll
        for (int o = 0; o < 4; ++o) {
            int rc = min(max(acc[p][o], -1), 1);
            pack |= (uint32_t)(rc & 0xff) << (8 * o);
        }
        a3[(((size_t)ln * 8 + ocg) * 252 + (oy0 + p)) * 252 + ox] = pack;
    }
}

// ---- layer 4: conv(32->2) ternary, dot4, 2 output rows/thread, f32 out ---
__global__ __launch_bounds__(256) void k4(const uint32_t* __restrict__ a3,
                                          const int* __restrict__ w4p,
                                          float* __restrict__ out, int n0) {
    int ox = threadIdx.x; if (ox >= 250) return;
    int oy0 = blockIdx.y * 2;       // 0..248, 125 tiles
    int ln = blockIdx.z;

    int acc[2][2];
#pragma unroll
    for (int p = 0; p < 2; ++p)
#pragma unroll
        for (int o = 0; o < 2; ++o) acc[p][o] = 0;

#pragma unroll
    for (int icg = 0; icg < 8; ++icg) {
        uint32_t r[4][3];
        const uint32_t* base = a3 + (((size_t)ln * 8 + icg) * 252 + oy0) * 252 + ox;
#pragma unroll
        for (int j = 0; j < 4; ++j)
#pragma unroll
            for (int c = 0; c < 3; ++c) r[j][c] = base[j * 252 + c];

#pragma unroll
        for (int o = 0; o < 2; ++o) {
            const int* wb = w4p + ((o * 8 + icg) * 9);
#pragma unroll
            for (int ky = 0; ky < 3; ++ky) {
#pragma unroll
                for (int p = 0; p < 2; ++p) {
                    acc[p][o] = dot4((int)r[p + ky][0], wb[ky * 3 + 0], acc[p][o]);
                    acc[p][o] = dot4((int)r[p + ky][1], wb[ky * 3 + 1], acc[p][o]);
                    acc[p][o] = dot4((int)r[p + ky][2], wb[ky * 3 + 2], acc[p][o]);
                }
            }
        }
    }
    size_t gn = (size_t)(n0 + ln);
#pragma unroll
    for (int p = 0; p < 2; ++p)
#pragma unroll
        for (int o = 0; o < 2; ++o) {
            float v = fminf(fmaxf((float)acc[p][o], -1.f), 1.f);
            out[((gn * 2 + o) * 250 + (oy0 + p)) * 250 + ox] = v;
        }
}

extern "C" void kernel_launch(void* const* d_in, const int* in_sizes, int n_in,
                              void* d_out, int out_size, void* d_ws, size_t ws_size,
                              hipStream_t stream) {
    const float* x  = (const float*)d_in[0];
    const float* w1 = (const float*)d_in[1];
    const float* w2 = (const float*)d_in[2];
    const float* w3 = (const float*)d_in[3];
    const float* w4 = (const float*)d_in[4];
    char* ws = (char*)d_ws;

    int*   w2p = (int*)(ws + WOFF_W2P);
    int*   w3p = (int*)(ws + WOFF_W3P);
    int*   w4p = (int*)(ws + WOFF_W4P);
    float* w1s = (float*)(ws + WOFF_W1S);
    float* out = (float*)d_out;

    size_t per = (size_t)A1_PB + (size_t)A2_PB + (size_t)A3_PB;
    int NC = 32;
    while (NC > 1 && (size_t)WEIGHTS_BYTES + (size_t)NC * per > ws_size) NC >>= 1;

    uint32_t* A1 = (uint32_t*)(ws + WEIGHTS_BYTES);
    uint32_t* A2 = (uint32_t*)(ws + WEIGHTS_BYTES + (size_t)NC * A1_PB);
    uint32_t* A3 = (uint32_t*)(ws + WEIGHTS_BYTES + (size_t)NC * (A1_PB + A2_PB));

    kprep<<<1, 256, 0, stream>>>(w1, w2, w3, w4, w2p, w3p, w4p, w1s);
    for (int n0 = 0; n0 < 32; n0 += NC) {
        k1<<<dim3(1, 256, NC),     256, 0, stream>>>(x, w1s, A1, n0);
        k2<<<dim3(1, 127, NC * 4), 256, 0, stream>>>(A1, w2p, A2);
        k3<<<dim3(1, 63,  NC * 8), 256, 0, stream>>>(A2, w3p, A3);
        k4<<<dim3(1, 125, NC),     256, 0, stream>>>(A3, w4p, out, n0);
    }
}

// Round 8
// 195.966 us; speedup vs baseline: 18.7773x; 1.0090x over previous
//
#include <hip/hip_runtime.h>
#include <hip/hip_bf16.h>
#include <cstdint>

// ---------------------------------------------------------------------------
// Binarized CNN. Verified numerics (R5-R7 passed bit-exact):
//  - binarize(x) == sign(x) exactly; layers 2-4 are exact small-int math in
//    any order -> packed 4 int8 channels/dword + v_dot4_i32_i8, any order.
//  - conv1 MUST keep f32 accumulation in k-ascending order
//    k = (ky*3+kx)*3+ic (Eigen/XLA-CPU im2col) — k1 is bit-identical to the
//    passing version. DO NOT REORDER k1's accumulation.
//  - R8: 2D output blocking (4x2 in k3, 2x2 in k2/k4) + uint2 loads/stores.
//    Per-output dword loads k3: 4.5 -> 1.5.
// ---------------------------------------------------------------------------

#define WOFF_W2P 0          // int32[16*2*9]
#define WOFF_W3P 8192       // int32[32*4*9]
#define WOFF_W4P 16384      // int32[2*8*9]
#define WOFF_W1S 20480      // float[216]
#define WEIGHTS_BYTES 32768

#define A1_PB (2*256*256*4)     // bytes per batch (packed u32)
#define A2_PB (4*254*254*4)
#define A3_PB (8*252*252*4)

__device__ __forceinline__ int dot4(int a, int b, int c) {
#if __has_builtin(__builtin_amdgcn_sdot4)
    return __builtin_amdgcn_sdot4(a, b, c, false);
#else
    int s = c;
#pragma unroll
    for (int j = 0; j < 4; ++j) {
        int av = (a << (24 - 8 * j)) >> 24;
        int bv = (b << (24 - 8 * j)) >> 24;
        s += av * bv;
    }
    return s;
#endif
}

__device__ __forceinline__ int fsign(float w) {
    return (w > 0.f) ? 1 : ((w < 0.f) ? -1 : 0);
}

// ---- weight prep: pack signs into dot4-ready dwords ----------------------
__global__ __launch_bounds__(256) void kprep(const float* __restrict__ w1,
                                             const float* __restrict__ w2,
                                             const float* __restrict__ w3,
                                             const float* __restrict__ w4,
                                             int* __restrict__ w2p,
                                             int* __restrict__ w3p,
                                             int* __restrict__ w4p,
                                             float* __restrict__ w1s) {
    int t = threadIdx.x;
    for (int idx = t; idx < 16 * 2 * 9; idx += 256) {
        int k = idx % 9, icg = (idx / 9) % 2, oc = idx / 18;
        int pack = 0;
#pragma unroll
        for (int j = 0; j < 4; ++j)
            pack |= (fsign(w2[(oc * 8 + icg * 4 + j) * 9 + k]) & 0xff) << (8 * j);
        w2p[idx] = pack;
    }
    for (int idx = t; idx < 32 * 4 * 9; idx += 256) {
        int k = idx % 9, icg = (idx / 9) % 4, oc = idx / 36;
        int pack = 0;
#pragma unroll
        for (int j = 0; j < 4; ++j)
            pack |= (fsign(w3[(oc * 16 + icg * 4 + j) * 9 + k]) & 0xff) << (8 * j);
        w3p[idx] = pack;
    }
    for (int idx = t; idx < 2 * 8 * 9; idx += 256) {
        int k = idx % 9, icg = (idx / 9) % 8, oc = idx / 72;
        int pack = 0;
#pragma unroll
        for (int j = 0; j < 4; ++j)
            pack |= (fsign(w4[(oc * 32 + icg * 4 + j) * 9 + k]) & 0xff) << (8 * j);
        w4p[idx] = pack;
    }
    for (int i = t; i < 216; i += 256) {
        float w = w1[i];
        w1s[i] = (w > 0.f) ? 1.f : ((w < 0.f) ? -1.f : 0.f);
    }
}

// ---- layer 1: pad(1)+conv(3->8)+hardtanh+maxpool2+sign, packed out -------
// BIT-IDENTICAL accumulation to the passing kernel: (ky,kx,ic)-ascending f32.
__global__ __launch_bounds__(256) void k1(const float* __restrict__ x,
                                          const float* __restrict__ w1s,
                                          uint32_t* __restrict__ a1, int n0) {
    int ox = threadIdx.x;   // 0..255
    int oy = blockIdx.y;    // 0..255
    int ln = blockIdx.z;
    const float* xn = x + (size_t)(n0 + ln) * 3 * 512 * 512;

    float v[3][16];
    int iy0 = 2 * oy - 1, ix0 = 2 * ox - 1;
    for (int ic = 0; ic < 3; ++ic) {
        const float* xc = xn + (size_t)ic * 512 * 512;
#pragma unroll
        for (int r = 0; r < 4; ++r) {
            int iy = iy0 + r;
            bool yok = ((unsigned)iy < 512u);
#pragma unroll
            for (int c = 0; c < 4; ++c) {
                int ix = ix0 + c;
                v[ic][r * 4 + c] = (yok && ((unsigned)ix < 512u))
                                       ? xc[(size_t)iy * 512 + ix] : 1.0f;
            }
        }
    }

    float acc[4][8];
#pragma unroll
    for (int p = 0; p < 4; ++p)
#pragma unroll
        for (int o = 0; o < 8; ++o) acc[p][o] = 0.f;

#pragma unroll
    for (int ky = 0; ky < 3; ++ky) {
#pragma unroll
        for (int kx = 0; kx < 3; ++kx) {
#pragma unroll
            for (int ic = 0; ic < 3; ++ic) {
                float v00 = v[ic][(ky + 0) * 4 + (kx + 0)];
                float v01 = v[ic][(ky + 0) * 4 + (kx + 1)];
                float v10 = v[ic][(ky + 1) * 4 + (kx + 0)];
                float v11 = v[ic][(ky + 1) * 4 + (kx + 1)];
#pragma unroll
                for (int o = 0; o < 8; ++o) {
                    float w = w1s[o * 27 + ic * 9 + ky * 3 + kx];
                    acc[0][o] += w * v00;
                    acc[1][o] += w * v01;
                    acc[2][o] += w * v10;
                    acc[3][o] += w * v11;
                }
            }
        }
    }

    uint32_t d0 = 0, d1 = 0;
#pragma unroll
    for (int o = 0; o < 8; ++o) {
        float m = fmaxf(fmaxf(acc[0][o], acc[1][o]), fmaxf(acc[2][o], acc[3][o]));
        int sg = (m > 0.f) ? 1 : ((m < 0.f) ? -1 : 0);
        if (o < 4) d0 |= (uint32_t)(sg & 0xff) << (8 * o);
        else       d1 |= (uint32_t)(sg & 0xff) << (8 * (o - 4));
    }
    size_t base = (((size_t)ln * 2) * 256 + oy) * 256 + ox;
    a1[base]             = d0;
    a1[base + 256 * 256] = d1;
}

// ---- layer 2: conv(8->16) ternary, dot4, 2x2 outputs/thread --------------
__global__ __launch_bounds__(128) void k2(const uint32_t* __restrict__ a1,
                                          const int* __restrict__ w2p,
                                          uint32_t* __restrict__ a2) {
    int ox = threadIdx.x; if (ox >= 127) return;   // 127*2 = 254 cols
    int oy0 = blockIdx.y * 2;                      // 127 tiles
    int z = blockIdx.z;                            // ln*4 + ocg
    int ln = z >> 2, ocg = z & 3;

    int acc[2][2][4] = {};
#pragma unroll
    for (int icg = 0; icg < 2; ++icg) {
        uint32_t r[4][4];
        const uint32_t* base = a1 + (((size_t)ln * 2 + icg) * 256 + oy0) * 256 + 2 * ox;
#pragma unroll
        for (int j = 0; j < 4; ++j) {
            uint2 lo = *(const uint2*)(base + (size_t)j * 256);
            uint2 hi = *(const uint2*)(base + (size_t)j * 256 + 2);
            r[j][0] = lo.x; r[j][1] = lo.y; r[j][2] = hi.x; r[j][3] = hi.y;
        }
#pragma unroll
        for (int o = 0; o < 4; ++o) {
            const int* wb = w2p + (((ocg * 4 + o) * 2 + icg) * 9);
#pragma unroll
            for (int ky = 0; ky < 3; ++ky) {
#pragma unroll
                for (int p = 0; p < 2; ++p) {
#pragma unroll
                    for (int q = 0; q < 2; ++q) {
                        acc[p][q][o] = dot4((int)r[p + ky][q + 0], wb[ky * 3 + 0], acc[p][q][o]);
                        acc[p][q][o] = dot4((int)r[p + ky][q + 1], wb[ky * 3 + 1], acc[p][q][o]);
                        acc[p][q][o] = dot4((int)r[p + ky][q + 2], wb[ky * 3 + 2], acc[p][q][o]);
                    }
                }
            }
        }
    }
#pragma unroll
    for (int p = 0; p < 2; ++p) {
        uint2 w;
        uint32_t pk[2];
#pragma unroll
        for (int q = 0; q < 2; ++q) {
            uint32_t pack = 0;
#pragma unroll
            for (int o = 0; o < 4; ++o) {
                int rc = min(max(acc[p][q][o], -1), 1);
                pack |= (uint32_t)(rc & 0xff) << (8 * o);
            }
            pk[q] = pack;
        }
        w.x = pk[0]; w.y = pk[1];
        *(uint2*)(a2 + (((size_t)ln * 4 + ocg) * 254 + (oy0 + p)) * 254 + 2 * ox) = w;
    }
}

// ---- layer 3: conv(16->32) ternary, dot4, 4x2 outputs/thread -------------
__global__ __launch_bounds__(128) void k3(const uint32_t* __restrict__ a2,
                                          const int* __restrict__ w3p,
                                          uint32_t* __restrict__ a3) {
    int ox = threadIdx.x; if (ox >= 126) return;   // 126*2 = 252 cols
    int oy0 = blockIdx.y * 4;                      // 63 tiles
    int z = blockIdx.z;                            // ln*8 + ocg
    int ln = z >> 3, ocg = z & 7;

    int acc[4][2][4] = {};
#pragma unroll
    for (int icg = 0; icg < 4; ++icg) {
        uint32_t r[6][4];
        const uint32_t* base = a2 + (((size_t)ln * 4 + icg) * 254 + oy0) * 254 + 2 * ox;
#pragma unroll
        for (int j = 0; j < 6; ++j) {
            uint2 lo = *(const uint2*)(base + (size_t)j * 254);
            uint2 hi = *(const uint2*)(base + (size_t)j * 254 + 2);
            r[j][0] = lo.x; r[j][1] = lo.y; r[j][2] = hi.x; r[j][3] = hi.y;
        }
#pragma unroll
        for (int o = 0; o < 4; ++o) {
            const int* wb = w3p + (((ocg * 4 + o) * 4 + icg) * 9);
#pragma unroll
            for (int ky = 0; ky < 3; ++ky) {
#pragma unroll
                for (int p = 0; p < 4; ++p) {
#pragma unroll
                    for (int q = 0; q < 2; ++q) {
                        acc[p][q][o] = dot4((int)r[p + ky][q + 0], wb[ky * 3 + 0], acc[p][q][o]);
                        acc[p][q][o] = dot4((int)r[p + ky][q + 1], wb[ky * 3 + 1], acc[p][q][o]);
                        acc[p][q][o] = dot4((int)r[p + ky][q + 2], wb[ky * 3 + 2], acc[p][q][o]);
                    }
                }
            }
        }
    }
#pragma unroll
    for (int p = 0; p < 4; ++p) {
        uint2 w;
        uint32_t pk[2];
#pragma unroll
        for (int q = 0; q < 2; ++q) {
            uint32_t pack = 0;
#pragma unroll
            for (int o = 0; o < 4; ++o) {
                int rc = min(max(acc[p][q][o], -1), 1);
                pack |= (uint32_t)(rc & 0xff) << (8 * o);
            }
            pk[q] = pack;
        }
        w.x = pk[0]; w.y = pk[1];
        *(uint2*)(a3 + (((size_t)ln * 8 + ocg) * 252 + (oy0 + p)) * 252 + 2 * ox) = w;
    }
}

// ---- layer 4: conv(32->2) ternary, dot4, 2x2 outputs/thread, f32 out -----
__global__ __launch_bounds__(128) void k4(const uint32_t* __restrict__ a3,
                                          const int* __restrict__ w4p,
                                          float* __restrict__ out, int n0) {
    int ox = threadIdx.x; if (ox >= 125) return;   // 125*2 = 250 cols
    int oy0 = blockIdx.y * 2;                      // 125 tiles
    int ln = blockIdx.z;

    int acc[2][2][2] = {};
#pragma unroll
    for (int icg = 0; icg < 8; ++icg) {
        uint32_t r[4][4];
        const uint32_t* base = a3 + (((size_t)ln * 8 + icg) * 252 + oy0) * 252 + 2 * ox;
#pragma unroll
        for (int j = 0; j < 4; ++j) {
            uint2 lo = *(const uint2*)(base + (size_t)j * 252);
            uint2 hi = *(const uint2*)(base + (size_t)j * 252 + 2);
            r[j][0] = lo.x; r[j][1] = lo.y; r[j][2] = hi.x; r[j][3] = hi.y;
        }
#pragma unroll
        for (int o = 0; o < 2; ++o) {
            const int* wb = w4p + ((o * 8 + icg) * 9);
#pragma unroll
            for (int ky = 0; ky < 3; ++ky) {
#pragma unroll
                for (int p = 0; p < 2; ++p) {
#pragma unroll
                    for (int q = 0; q < 2; ++q) {
                        acc[p][q][o] = dot4((int)r[p + ky][q + 0], wb[ky * 3 + 0], acc[p][q][o]);
                        acc[p][q][o] = dot4((int)r[p + ky][q + 1], wb[ky * 3 + 1], acc[p][q][o]);
                        acc[p][q][o] = dot4((int)r[p + ky][q + 2], wb[ky * 3 + 2], acc[p][q][o]);
                    }
                }
            }
        }
    }
    size_t gn = (size_t)(n0 + ln);
#pragma unroll
    for (int o = 0; o < 2; ++o)
#pragma unroll
        for (int p = 0; p < 2; ++p) {
            float2 w;
            w.x = fminf(fmaxf((float)acc[p][0][o], -1.f), 1.f);
            w.y = fminf(fmaxf((float)acc[p][1][o], -1.f), 1.f);
            *(float2*)(out + ((gn * 2 + o) * 250 + (oy0 + p)) * 250 + 2 * ox) = w;
        }
}

extern "C" void kernel_launch(void* const* d_in, const int* in_sizes, int n_in,
                              void* d_out, int out_size, void* d_ws, size_t ws_size,
                              hipStream_t stream) {
    const float* x  = (const float*)d_in[0];
    const float* w1 = (const float*)d_in[1];
    const float* w2 = (const float*)d_in[2];
    const float* w3 = (const float*)d_in[3];
    const float* w4 = (const float*)d_in[4];
    char* ws = (char*)d_ws;

    int*   w2p = (int*)(ws + WOFF_W2P);
    int*   w3p = (int*)(ws + WOFF_W3P);
    int*   w4p = (int*)(ws + WOFF_W4P);
    float* w1s = (float*)(ws + WOFF_W1S);
    float* out = (float*)d_out;

    size_t per = (size_t)A1_PB + (size_t)A2_PB + (size_t)A3_PB;
    int NC = 32;
    while (NC > 1 && (size_t)WEIGHTS_BYTES + (size_t)NC * per > ws_size) NC >>= 1;

    uint32_t* A1 = (uint32_t*)(ws + WEIGHTS_BYTES);
    uint32_t* A2 = (uint32_t*)(ws + WEIGHTS_BYTES + (size_t)NC * A1_PB);
    uint32_t* A3 = (uint32_t*)(ws + WEIGHTS_BYTES + (size_t)NC * (A1_PB + A2_PB));

    kprep<<<1, 256, 0, stream>>>(w1, w2, w3, w4, w2p, w3p, w4p, w1s);
    for (int n0 = 0; n0 < 32; n0 += NC) {
        k1<<<dim3(1, 256, NC),     256, 0, stream>>>(x, w1s, A1, n0);
        k2<<<dim3(1, 127, NC * 4), 128, 0, stream>>>(A1, w2p, A2);
        k3<<<dim3(1, 63,  NC * 8), 128, 0, stream>>>(A2, w3p, A3);
        k4<<<dim3(1, 125, NC),     128, 0, stream>>>(A3, w4p, out, n0);
    }
}

// Round 9
// 191.527 us; speedup vs baseline: 19.2125x; 1.0232x over previous
//
#include <hip/hip_runtime.h>
#include <hip/hip_bf16.h>
#include <cstdint>

// ---------------------------------------------------------------------------
// Binarized CNN. Verified numerics (R5-R8 passed bit-exact):
//  - binarize(x) == sign(x) exactly; layers 2-4 are exact small-int math in
//    any order -> any packing / instruction choice is safe.
//  - conv1 MUST keep f32 accumulation in k-ascending order
//    k = (ky*3+kx)*3+ic (Eigen/XLA-CPU im2col) — k1 is bit-identical to the
//    passing version. DO NOT REORDER k1's accumulation.
//  - R9: k2/k3 -> MFMA (v_mfma_i32_32x32x32_i8), per-tap GEMM:
//      C[32px x 32oc] += A[32px x K=ic(pad32)] * B[K x oc], 9 taps.
//    A staged in LDS [row][x][icg] (ds_read_b128 per lane); B prepacked
//    per-lane in kprep (zero-pad invalid ic/oc). Epilogue transposes C via
//    LDS to repack 4 oc/dword. k1/k4 unchanged.
// ---------------------------------------------------------------------------

typedef __attribute__((ext_vector_type(4)))  int int4v;
typedef __attribute__((ext_vector_type(16))) int int16v;

#define WOFF_W2M 0          // int[9*64*4]  = 9216 B  (MFMA B-frag table L2)
#define WOFF_W3M 10240      // int[9*64*4]  = 9216 B  (MFMA B-frag table L3)
#define WOFF_W4P 20480      // int[2*8*9]   = 576 B   (dot4 packs L4)
#define WOFF_W1S 22528      // float[216]
#define WEIGHTS_BYTES 32768

#define A1_PB (2*256*256*4)     // bytes per batch (packed u32, 4 ch/dword)
#define A2_PB (4*254*254*4)
#define A3_PB (8*252*252*4)

__device__ __forceinline__ int dot4(int a, int b, int c) {
#if __has_builtin(__builtin_amdgcn_sdot4)
    return __builtin_amdgcn_sdot4(a, b, c, false);
#else
    int s = c;
#pragma unroll
    for (int j = 0; j < 4; ++j) {
        int av = (a << (24 - 8 * j)) >> 24;
        int bv = (b << (24 - 8 * j)) >> 24;
        s += av * bv;
    }
    return s;
#endif
}

__device__ __forceinline__ int fsign(float w) {
    return (w > 0.f) ? 1 : ((w < 0.f) ? -1 : 0);
}

// ---- weight prep ---------------------------------------------------------
__global__ __launch_bounds__(256) void kprep(const float* __restrict__ w1,
                                             const float* __restrict__ w2,
                                             const float* __restrict__ w3,
                                             const float* __restrict__ w4,
                                             int* __restrict__ w2m,
                                             int* __restrict__ w3m,
                                             int* __restrict__ w4p,
                                             float* __restrict__ w1s) {
    int tid = threadIdx.x;
    // MFMA B-fragment tables: entry (tap, lane) = 4 dwords = 16 K-bytes.
    // Lane l supplies col oc = l&31, K bytes ic = (l>>5)*16 + j (j=0..15).
    // Invalid (oc, ic) -> 0 (handles L2's 8 ic / 16 oc padding for free).
    for (int idx = tid; idx < 576; idx += 256) {
        int t = idx / 64, l = idx % 64;
        int oc = l & 31, icb = (l >> 5) * 16;
        int wd[4] = {0, 0, 0, 0};
        for (int j = 0; j < 16; ++j) {
            int ic = icb + j;
            int s = (oc < 16 && ic < 8) ? fsign(w2[(oc * 8 + ic) * 9 + t]) : 0;
            wd[j >> 2] |= (s & 0xff) << (8 * (j & 3));
        }
        w2m[idx * 4 + 0] = wd[0]; w2m[idx * 4 + 1] = wd[1];
        w2m[idx * 4 + 2] = wd[2]; w2m[idx * 4 + 3] = wd[3];
    }
    for (int idx = tid; idx < 576; idx += 256) {
        int t = idx / 64, l = idx % 64;
        int oc = l & 31, icb = (l >> 5) * 16;
        int wd[4] = {0, 0, 0, 0};
        for (int j = 0; j < 16; ++j) {
            int ic = icb + j;
            int s = (ic < 16) ? fsign(w3[(oc * 16 + ic) * 9 + t]) : 0;
            wd[j >> 2] |= (s & 0xff) << (8 * (j & 3));
        }
        w3m[idx * 4 + 0] = wd[0]; w3m[idx * 4 + 1] = wd[1];
        w3m[idx * 4 + 2] = wd[2]; w3m[idx * 4 + 3] = wd[3];
    }
    // L4 dot4 packs: w4p[(oc*8+icg)*9+k] byte j = sign(w4[(oc*32+icg*4+j)*9+k])
    for (int idx = tid; idx < 2 * 8 * 9; idx += 256) {
        int k = idx % 9, icg = (idx / 9) % 8, oc = idx / 72;
        int pack = 0;
#pragma unroll
        for (int j = 0; j < 4; ++j)
            pack |= (fsign(w4[(oc * 32 + icg * 4 + j) * 9 + k]) & 0xff) << (8 * j);
        w4p[idx] = pack;
    }
    for (int i = tid; i < 216; i += 256) {
        float w = w1[i];
        w1s[i] = (w > 0.f) ? 1.f : ((w < 0.f) ? -1.f : 0.f);
    }
}

// ---- layer 1: pad(1)+conv(3->8)+hardtanh+maxpool2+sign, packed out -------
// BIT-IDENTICAL accumulation to the passing kernel: (ky,kx,ic)-ascending f32.
__global__ __launch_bounds__(256) void k1(const float* __restrict__ x,
                                          const float* __restrict__ w1s,
                                          uint32_t* __restrict__ a1, int n0) {
    int ox = threadIdx.x;   // 0..255
    int oy = blockIdx.y;    // 0..255
    int ln = blockIdx.z;
    const float* xn = x + (size_t)(n0 + ln) * 3 * 512 * 512;

    float v[3][16];
    int iy0 = 2 * oy - 1, ix0 = 2 * ox - 1;
    for (int ic = 0; ic < 3; ++ic) {
        const float* xc = xn + (size_t)ic * 512 * 512;
#pragma unroll
        for (int r = 0; r < 4; ++r) {
            int iy = iy0 + r;
            bool yok = ((unsigned)iy < 512u);
#pragma unroll
            for (int c = 0; c < 4; ++c) {
                int ix = ix0 + c;
                v[ic][r * 4 + c] = (yok && ((unsigned)ix < 512u))
                                       ? xc[(size_t)iy * 512 + ix] : 1.0f;
            }
        }
    }

    float acc[4][8];
#pragma unroll
    for (int p = 0; p < 4; ++p)
#pragma unroll
        for (int o = 0; o < 8; ++o) acc[p][o] = 0.f;

#pragma unroll
    for (int ky = 0; ky < 3; ++ky) {
#pragma unroll
        for (int kx = 0; kx < 3; ++kx) {
#pragma unroll
            for (int ic = 0; ic < 3; ++ic) {
                float v00 = v[ic][(ky + 0) * 4 + (kx + 0)];
                float v01 = v[ic][(ky + 0) * 4 + (kx + 1)];
                float v10 = v[ic][(ky + 1) * 4 + (kx + 0)];
                float v11 = v[ic][(ky + 1) * 4 + (kx + 1)];
#pragma unroll
                for (int o = 0; o < 8; ++o) {
                    float w = w1s[o * 27 + ic * 9 + ky * 3 + kx];
                    acc[0][o] += w * v00;
                    acc[1][o] += w * v01;
                    acc[2][o] += w * v10;
                    acc[3][o] += w * v11;
                }
            }
        }
    }

    uint32_t d0 = 0, d1 = 0;
#pragma unroll
    for (int o = 0; o < 8; ++o) {
        float m = fmaxf(fmaxf(acc[0][o], acc[1][o]), fmaxf(acc[2][o], acc[3][o]));
        int sg = (m > 0.f) ? 1 : ((m < 0.f) ? -1 : 0);
        if (o < 4) d0 |= (uint32_t)(sg & 0xff) << (8 * o);
        else       d1 |= (uint32_t)(sg & 0xff) << (8 * (o - 4));
    }
    size_t base = (((size_t)ln * 2) * 256 + oy) * 256 + ox;
    a1[base]             = d0;
    a1[base + 256 * 256] = d1;
}

// ---- layers 2/3: ternary conv via MFMA i32_32x32x32_i8 -------------------
// One wave computes one output tile: 32 consecutive x, one row y, all oc.
// Per tap t=(ky,kx): A[m=xl, k=ic] = act(y+ky, x0+m+kx) (K zero-padded),
// B[k, n=oc] from the prepacked table. 9 MFMAs per tile.
// ICG: input packed planes; INW/OUTW: widths; OCGO: output packed planes.
template<int ICG, int INW, int OUTW, int OCGO>
__global__ __launch_bounds__(256) void kconv(const uint32_t* __restrict__ ain,
                                             const int* __restrict__ wm,
                                             uint32_t* __restrict__ aout) {
    __shared__ uint32_t st[4][3][36][4];   // [wave][row][x][icg] staged acts
    __shared__ uint32_t ep[4][32][9];      // [wave][x][ocg] epilogue repack
    int w    = threadIdx.x >> 6;
    int lane = threadIdx.x & 63;
    int x0 = blockIdx.x * 32;
    int y  = blockIdx.y * 4 + w;           // output row (may overshoot; guarded)
    int ln = blockIdx.z;

    // B fragments for all 9 taps (per-lane prepacked)
    const int4v* wmv = (const int4v*)wm;
    int4v bfr[9];
#pragma unroll
    for (int t = 0; t < 9; ++t) bfr[t] = wmv[t * 64 + lane];

    // stage rows y..y+2, x0..x0+33 (pad to 36), planes 0..3 (pad ICG..3 = 0)
    const uint32_t* abase = ain + (size_t)ln * ICG * INW * INW;
    for (int idx = lane; idx < 432; idx += 64) {
        int icg = idx & 3, tmp = idx >> 2;
        int xx = tmp % 36, row = tmp / 36;
        int gy = y + row, gx = x0 + xx;
        uint32_t val = 0;
        if (icg < ICG && xx < 34 && gx < INW && gy < INW)
            val = abase[((size_t)icg * INW + gy) * INW + gx];
        st[w][row][xx][icg] = val;
    }
    // wave-local producer/consumer: lgkmcnt ordering only, no barrier needed

    int16v acc = {};
    int xl = lane & 31;
#pragma unroll
    for (int ky = 0; ky < 3; ++ky) {
#pragma unroll
        for (int kx = 0; kx < 3; ++kx) {
            // all lanes load the same pixel's 4 icg dwords; lanes>=32 supply
            // K 16..31 whose B-bytes are 0, so their A content is ignored.
            int4v a = *(const int4v*)&st[w][ky][xl + kx][0];
            acc = __builtin_amdgcn_mfma_i32_32x32x32_i8(a, bfr[ky * 3 + kx], acc, 0, 0, 0);
        }
    }

    // epilogue: clamp to [-1,1], transpose via LDS, pack 4 oc per dword
    signed char* epb = (signed char*)&ep[w][0][0];
    int oc = lane & 31;
#pragma unroll
    for (int r = 0; r < 16; ++r) {
        int m = (r & 3) + 8 * (r >> 2) + 4 * (lane >> 5);   // pixel index
        int val = min(max(acc[r], -1), 1);
        epb[m * 36 + oc] = (signed char)val;
    }
    // same wave reads what it wrote (cross-lane) -> lgkmcnt-ordered, lockstep
    if (y < OUTW && x0 + xl < OUTW) {
#pragma unroll
        for (int it = 0; it < 4; ++it) {
            int ocg = (lane >> 5) * 4 + it;
            if (ocg < OCGO)
                aout[(((size_t)ln * OCGO + ocg) * OUTW + y) * OUTW + x0 + xl] =
                    ep[w][xl][ocg];
        }
    }
}

// ---- layer 4: conv(32->2) ternary, dot4, 2x2 outputs/thread, f32 out -----
__global__ __launch_bounds__(128) void k4(const uint32_t* __restrict__ a3,
                                          const int* __restrict__ w4p,
                                          float* __restrict__ out, int n0) {
    int ox = threadIdx.x; if (ox >= 125) return;   // 125*2 = 250 cols
    int oy0 = blockIdx.y * 2;                      // 125 tiles
    int ln = blockIdx.z;

    int acc[2][2][2] = {};
#pragma unroll
    for (int icg = 0; icg < 8; ++icg) {
        uint32_t r[4][4];
        const uint32_t* base = a3 + (((size_t)ln * 8 + icg) * 252 + oy0) * 252 + 2 * ox;
#pragma unroll
        for (int j = 0; j < 4; ++j) {
            uint2 lo = *(const uint2*)(base + (size_t)j * 252);
            uint2 hi = *(const uint2*)(base + (size_t)j * 252 + 2);
            r[j][0] = lo.x; r[j][1] = lo.y; r[j][2] = hi.x; r[j][3] = hi.y;
        }
#pragma unroll
        for (int o = 0; o < 2; ++o) {
            const int* wb = w4p + ((o * 8 + icg) * 9);
#pragma unroll
            for (int ky = 0; ky < 3; ++ky) {
#pragma unroll
                for (int p = 0; p < 2; ++p) {
#pragma unroll
                    for (int q = 0; q < 2; ++q) {
                        acc[p][q][o] = dot4((int)r[p + ky][q + 0], wb[ky * 3 + 0], acc[p][q][o]);
                        acc[p][q][o] = dot4((int)r[p + ky][q + 1], wb[ky * 3 + 1], acc[p][q][o]);
                        acc[p][q][o] = dot4((int)r[p + ky][q + 2], wb[ky * 3 + 2], acc[p][q][o]);
                    }
                }
            }
        }
    }
    size_t gn = (size_t)(n0 + ln);
#pragma unroll
    for (int o = 0; o < 2; ++o)
#pragma unroll
        for (int p = 0; p < 2; ++p) {
            float2 w;
            w.x = fminf(fmaxf((float)acc[p][0][o], -1.f), 1.f);
            w.y = fminf(fmaxf((float)acc[p][1][o], -1.f), 1.f);
            *(float2*)(out + ((gn * 2 + o) * 250 + (oy0 + p)) * 250 + 2 * ox) = w;
        }
}

extern "C" void kernel_launch(void* const* d_in, const int* in_sizes, int n_in,
                              void* d_out, int out_size, void* d_ws, size_t ws_size,
                              hipStream_t stream) {
    const float* x  = (const float*)d_in[0];
    const float* w1 = (const float*)d_in[1];
    const float* w2 = (const float*)d_in[2];
    const float* w3 = (const float*)d_in[3];
    const float* w4 = (const float*)d_in[4];
    char* ws = (char*)d_ws;

    int*   w2m = (int*)(ws + WOFF_W2M);
    int*   w3m = (int*)(ws + WOFF_W3M);
    int*   w4p = (int*)(ws + WOFF_W4P);
    float* w1s = (float*)(ws + WOFF_W1S);
    float* out = (float*)d_out;

    size_t per = (size_t)A1_PB + (size_t)A2_PB + (size_t)A3_PB;
    int NC = 32;
    while (NC > 1 && (size_t)WEIGHTS_BYTES + (size_t)NC * per > ws_size) NC >>= 1;

    uint32_t* A1 = (uint32_t*)(ws + WEIGHTS_BYTES);
    uint32_t* A2 = (uint32_t*)(ws + WEIGHTS_BYTES + (size_t)NC * A1_PB);
    uint32_t* A3 = (uint32_t*)(ws + WEIGHTS_BYTES + (size_t)NC * (A1_PB + A2_PB));

    kprep<<<1, 256, 0, stream>>>(w1, w2, w3, w4, w2m, w3m, w4p, w1s);
    for (int n0 = 0; n0 < 32; n0 += NC) {
        k1<<<dim3(1, 256, NC), 256, 0, stream>>>(x, w1s, A1, n0);
        // L2: 2 in-planes, 256 -> 254, 4 out-planes; rows grouped 4/block
        kconv<2, 256, 254, 4><<<dim3(8, 64, NC), 256, 0, stream>>>(A1, w2m, A2);
        // L3: 4 in-planes, 254 -> 252, 8 out-planes
        kconv<4, 254, 252, 8><<<dim3(8, 63, NC), 256, 0, stream>>>(A2, w3m, A3);
        k4<<<dim3(1, 125, NC), 128, 0, stream>>>(A3, w4p, out, n0);
    }
}

// Round 10
// 190.733 us; speedup vs baseline: 19.2925x; 1.0042x over previous
//
#include <hip/hip_runtime.h>
#include <hip/hip_bf16.h>
#include <cstdint>

// ---------------------------------------------------------------------------
// Binarized CNN. Verified numerics (R5-R9 passed bit-exact):
//  - binarize(x) == sign(x) exactly; layers 2-4 are exact small-int math in
//    any order -> any packing / instruction choice is safe.
//  - conv1 MUST keep f32 accumulation in k-ascending order
//    k = (ky*3+kx)*3+ic (Eigen/XLA-CPU im2col). The accumulation EXPRESSIONS
//    in k1 are bit-exactness contract: DO NOT REORDER. (R10 only changes how
//    the window is LOADED, not how it is summed.)
//  - k2/k3: MFMA v_mfma_i32_32x32x32_i8 per-tap GEMM (R9, verified).
//  - R10: k1 register-resident window (launch_bounds cap 128 VGPR) +
//    unguarded interior fast path with dense float2 middle-column loads.
// ---------------------------------------------------------------------------

typedef __attribute__((ext_vector_type(4)))  int int4v;
typedef __attribute__((ext_vector_type(16))) int int16v;

#define WOFF_W2M 0          // int[9*64*4]  = 9216 B  (MFMA B-frag table L2)
#define WOFF_W3M 10240      // int[9*64*4]  = 9216 B  (MFMA B-frag table L3)
#define WOFF_W4P 20480      // int[2*8*9]   = 576 B   (dot4 packs L4)
#define WOFF_W1S 22528      // float[216]
#define WEIGHTS_BYTES 32768

#define A1_PB (2*256*256*4)     // bytes per batch (packed u32, 4 ch/dword)
#define A2_PB (4*254*254*4)
#define A3_PB (8*252*252*4)

__device__ __forceinline__ int dot4(int a, int b, int c) {
#if __has_builtin(__builtin_amdgcn_sdot4)
    return __builtin_amdgcn_sdot4(a, b, c, false);
#else
    int s = c;
#pragma unroll
    for (int j = 0; j < 4; ++j) {
        int av = (a << (24 - 8 * j)) >> 24;
        int bv = (b << (24 - 8 * j)) >> 24;
        s += av * bv;
    }
    return s;
#endif
}

__device__ __forceinline__ int fsign(float w) {
    return (w > 0.f) ? 1 : ((w < 0.f) ? -1 : 0);
}

// ---- weight prep ---------------------------------------------------------
__global__ __launch_bounds__(256) void kprep(const float* __restrict__ w1,
                                             const float* __restrict__ w2,
                                             const float* __restrict__ w3,
                                             const float* __restrict__ w4,
                                             int* __restrict__ w2m,
                                             int* __restrict__ w3m,
                                             int* __restrict__ w4p,
                                             float* __restrict__ w1s) {
    int tid = threadIdx.x;
    // MFMA B-fragment tables: entry (tap, lane) = 4 dwords = 16 K-bytes.
    // Lane l supplies col oc = l&31, K bytes ic = (l>>5)*16 + j (j=0..15).
    for (int idx = tid; idx < 576; idx += 256) {
        int t = idx / 64, l = idx % 64;
        int oc = l & 31, icb = (l >> 5) * 16;
        int wd[4] = {0, 0, 0, 0};
        for (int j = 0; j < 16; ++j) {
            int ic = icb + j;
            int s = (oc < 16 && ic < 8) ? fsign(w2[(oc * 8 + ic) * 9 + t]) : 0;
            wd[j >> 2] |= (s & 0xff) << (8 * (j & 3));
        }
        w2m[idx * 4 + 0] = wd[0]; w2m[idx * 4 + 1] = wd[1];
        w2m[idx * 4 + 2] = wd[2]; w2m[idx * 4 + 3] = wd[3];
    }
    for (int idx = tid; idx < 576; idx += 256) {
        int t = idx / 64, l = idx % 64;
        int oc = l & 31, icb = (l >> 5) * 16;
        int wd[4] = {0, 0, 0, 0};
        for (int j = 0; j < 16; ++j) {
            int ic = icb + j;
            int s = (ic < 16) ? fsign(w3[(oc * 16 + ic) * 9 + t]) : 0;
            wd[j >> 2] |= (s & 0xff) << (8 * (j & 3));
        }
        w3m[idx * 4 + 0] = wd[0]; w3m[idx * 4 + 1] = wd[1];
        w3m[idx * 4 + 2] = wd[2]; w3m[idx * 4 + 3] = wd[3];
    }
    for (int idx = tid; idx < 2 * 8 * 9; idx += 256) {
        int k = idx % 9, icg = (idx / 9) % 8, oc = idx / 72;
        int pack = 0;
#pragma unroll
        for (int j = 0; j < 4; ++j)
            pack |= (fsign(w4[(oc * 32 + icg * 4 + j) * 9 + k]) & 0xff) << (8 * j);
        w4p[idx] = pack;
    }
    for (int i = tid; i < 216; i += 256) {
        float w = w1[i];
        w1s[i] = (w > 0.f) ? 1.f : ((w < 0.f) ? -1.f : 0.f);
    }
}

// ---- layer 1: pad(1)+conv(3->8)+hardtanh+maxpool2+sign, packed out -------
// Accumulation expressions BIT-IDENTICAL to the passing kernel:
// (ky,kx,ic)-ascending f32 chains. Only the window LOADS changed (R10).
__global__ __launch_bounds__(256, 2) void k1(const float* __restrict__ x,
                                             const float* __restrict__ w1s,
                                             uint32_t* __restrict__ a1, int n0) {
    int ox = threadIdx.x;   // 0..255
    int oy = blockIdx.y;    // 0..255
    int ln = blockIdx.z;
    const float* xn = x + (size_t)(n0 + ln) * 3 * 512 * 512;

    float v[3][16];
    int iy0 = 2 * oy - 1, ix0 = 2 * ox - 1;

    if (oy > 0 && oy < 255 && ox > 0 && ox < 255) {
        // interior: no bounds checks; middle two columns are even-indexed
        // -> dense float2 (coalesced across lanes)
#pragma unroll
        for (int ic = 0; ic < 3; ++ic) {
            const float* xc = xn + (size_t)ic * 512 * 512;
#pragma unroll
            for (int r = 0; r < 4; ++r) {
                const float* rp = xc + (size_t)(iy0 + r) * 512 + ix0;
                v[ic][r * 4 + 0] = rp[0];
                float2 m = *(const float2*)(rp + 1);
                v[ic][r * 4 + 1] = m.x;
                v[ic][r * 4 + 2] = m.y;
                v[ic][r * 4 + 3] = rp[3];
            }
        }
    } else {
        // border: original guarded path (pad value 1.0)
        for (int ic = 0; ic < 3; ++ic) {
            const float* xc = xn + (size_t)ic * 512 * 512;
#pragma unroll
            for (int r = 0; r < 4; ++r) {
                int iy = iy0 + r;
                bool yok = ((unsigned)iy < 512u);
#pragma unroll
                for (int c = 0; c < 4; ++c) {
                    int ix = ix0 + c;
                    v[ic][r * 4 + c] = (yok && ((unsigned)ix < 512u))
                                           ? xc[(size_t)iy * 512 + ix] : 1.0f;
                }
            }
        }
    }

    float acc[4][8];
#pragma unroll
    for (int p = 0; p < 4; ++p)
#pragma unroll
        for (int o = 0; o < 8; ++o) acc[p][o] = 0.f;

#pragma unroll
    for (int ky = 0; ky < 3; ++ky) {
#pragma unroll
        for (int kx = 0; kx < 3; ++kx) {
#pragma unroll
            for (int ic = 0; ic < 3; ++ic) {
                float v00 = v[ic][(ky + 0) * 4 + (kx + 0)];
                float v01 = v[ic][(ky + 0) * 4 + (kx + 1)];
                float v10 = v[ic][(ky + 1) * 4 + (kx + 0)];
                float v11 = v[ic][(ky + 1) * 4 + (kx + 1)];
#pragma unroll
                for (int o = 0; o < 8; ++o) {
                    float w = w1s[o * 27 + ic * 9 + ky * 3 + kx];
                    acc[0][o] += w * v00;
                    acc[1][o] += w * v01;
                    acc[2][o] += w * v10;
                    acc[3][o] += w * v11;
                }
            }
        }
    }

    uint32_t d0 = 0, d1 = 0;
#pragma unroll
    for (int o = 0; o < 8; ++o) {
        float m = fmaxf(fmaxf(acc[0][o], acc[1][o]), fmaxf(acc[2][o], acc[3][o]));
        int sg = (m > 0.f) ? 1 : ((m < 0.f) ? -1 : 0);
        if (o < 4) d0 |= (uint32_t)(sg & 0xff) << (8 * o);
        else       d1 |= (uint32_t)(sg & 0xff) << (8 * (o - 4));
    }
    size_t base = (((size_t)ln * 2) * 256 + oy) * 256 + ox;
    a1[base]             = d0;
    a1[base + 256 * 256] = d1;
}

// ---- layers 2/3: ternary conv via MFMA i32_32x32x32_i8 -------------------
template<int ICG, int INW, int OUTW, int OCGO>
__global__ __launch_bounds__(256) void kconv(const uint32_t* __restrict__ ain,
                                             const int* __restrict__ wm,
                                             uint32_t* __restrict__ aout) {
    __shared__ uint32_t st[4][3][36][4];   // [wave][row][x][icg] staged acts
    __shared__ uint32_t ep[4][32][9];      // [wave][x][ocg] epilogue repack
    int w    = threadIdx.x >> 6;
    int lane = threadIdx.x & 63;
    int x0 = blockIdx.x * 32;
    int y  = blockIdx.y * 4 + w;
    int ln = blockIdx.z;

    const int4v* wmv = (const int4v*)wm;
    int4v bfr[9];
#pragma unroll
    for (int t = 0; t < 9; ++t) bfr[t] = wmv[t * 64 + lane];

    const uint32_t* abase = ain + (size_t)ln * ICG * INW * INW;
    for (int idx = lane; idx < 432; idx += 64) {
        int icg = idx & 3, tmp = idx >> 2;
        int xx = tmp % 36, row = tmp / 36;
        int gy = y + row, gx = x0 + xx;
        uint32_t val = 0;
        if (icg < ICG && xx < 34 && gx < INW && gy < INW)
            val = abase[((size_t)icg * INW + gy) * INW + gx];
        st[w][row][xx][icg] = val;
    }

    int16v acc = {};
    int xl = lane & 31;
#pragma unroll
    for (int ky = 0; ky < 3; ++ky) {
#pragma unroll
        for (int kx = 0; kx < 3; ++kx) {
            int4v a = *(const int4v*)&st[w][ky][xl + kx][0];
            acc = __builtin_amdgcn_mfma_i32_32x32x32_i8(a, bfr[ky * 3 + kx], acc, 0, 0, 0);
        }
    }

    signed char* epb = (signed char*)&ep[w][0][0];
    int oc = lane & 31;
#pragma unroll
    for (int r = 0; r < 16; ++r) {
        int m = (r & 3) + 8 * (r >> 2) + 4 * (lane >> 5);
        int val = min(max(acc[r], -1), 1);
        epb[m * 36 + oc] = (signed char)val;
    }
    if (y < OUTW && x0 + xl < OUTW) {
#pragma unroll
        for (int it = 0; it < 4; ++it) {
            int ocg = (lane >> 5) * 4 + it;
            if (ocg < OCGO)
                aout[(((size_t)ln * OCGO + ocg) * OUTW + y) * OUTW + x0 + xl] =
                    ep[w][xl][ocg];
        }
    }
}

// ---- layer 4: conv(32->2) ternary, dot4, 2x2 outputs/thread, f32 out -----
__global__ __launch_bounds__(128) void k4(const uint32_t* __restrict__ a3,
                                          const int* __restrict__ w4p,
                                          float* __restrict__ out, int n0) {
    int ox = threadIdx.x; if (ox >= 125) return;
    int oy0 = blockIdx.y * 2;
    int ln = blockIdx.z;

    int acc[2][2][2] = {};
#pragma unroll
    for (int icg = 0; icg < 8; ++icg) {
        uint32_t r[4][4];
        const uint32_t* base = a3 + (((size_t)ln * 8 + icg) * 252 + oy0) * 252 + 2 * ox;
#pragma unroll
        for (int j = 0; j < 4; ++j) {
            uint2 lo = *(const uint2*)(base + (size_t)j * 252);
            uint2 hi = *(const uint2*)(base + (size_t)j * 252 + 2);
            r[j][0] = lo.x; r[j][1] = lo.y; r[j][2] = hi.x; r[j][3] = hi.y;
        }
#pragma unroll
        for (int o = 0; o < 2; ++o) {
            const int* wb = w4p + ((o * 8 + icg) * 9);
#pragma unroll
            for (int ky = 0; ky < 3; ++ky) {
#pragma unroll
                for (int p = 0; p < 2; ++p) {
#pragma unroll
                    for (int q = 0; q < 2; ++q) {
                        acc[p][q][o] = dot4((int)r[p + ky][q + 0], wb[ky * 3 + 0], acc[p][q][o]);
                        acc[p][q][o] = dot4((int)r[p + ky][q + 1], wb[ky * 3 + 1], acc[p][q][o]);
                        acc[p][q][o] = dot4((int)r[p + ky][q + 2], wb[ky * 3 + 2], acc[p][q][o]);
                    }
                }
            }
        }
    }
    size_t gn = (size_t)(n0 + ln);
#pragma unroll
    for (int o = 0; o < 2; ++o)
#pragma unroll
        for (int p = 0; p < 2; ++p) {
            float2 w;
            w.x = fminf(fmaxf((float)acc[p][0][o], -1.f), 1.f);
            w.y = fminf(fmaxf((float)acc[p][1][o], -1.f), 1.f);
            *(float2*)(out + ((gn * 2 + o) * 250 + (oy0 + p)) * 250 + 2 * ox) = w;
        }
}

extern "C" void kernel_launch(void* const* d_in, const int* in_sizes, int n_in,
                              void* d_out, int out_size, void* d_ws, size_t ws_size,
                              hipStream_t stream) {
    const float* x  = (const float*)d_in[0];
    const float* w1 = (const float*)d_in[1];
    const float* w2 = (const float*)d_in[2];
    const float* w3 = (const float*)d_in[3];
    const float* w4 = (const float*)d_in[4];
    char* ws = (char*)d_ws;

    int*   w2m = (int*)(ws + WOFF_W2M);
    int*   w3m = (int*)(ws + WOFF_W3M);
    int*   w4p = (int*)(ws + WOFF_W4P);
    float* w1s = (float*)(ws + WOFF_W1S);
    float* out = (float*)d_out;

    size_t per = (size_t)A1_PB + (size_t)A2_PB + (size_t)A3_PB;
    int NC = 32;
    while (NC > 1 && (size_t)WEIGHTS_BYTES + (size_t)NC * per > ws_size) NC >>= 1;

    uint32_t* A1 = (uint32_t*)(ws + WEIGHTS_BYTES);
    uint32_t* A2 = (uint32_t*)(ws + WEIGHTS_BYTES + (size_t)NC * A1_PB);
    uint32_t* A3 = (uint32_t*)(ws + WEIGHTS_BYTES + (size_t)NC * (A1_PB + A2_PB));

    kprep<<<1, 256, 0, stream>>>(w1, w2, w3, w4, w2m, w3m, w4p, w1s);
    for (int n0 = 0; n0 < 32; n0 += NC) {
        k1<<<dim3(1, 256, NC), 256, 0, stream>>>(x, w1s, A1, n0);
        kconv<2, 256, 254, 4><<<dim3(8, 64, NC), 256, 0, stream>>>(A1, w2m, A2);
        kconv<4, 254, 252, 8><<<dim3(8, 63, NC), 256, 0, stream>>>(A2, w3m, A3);
        k4<<<dim3(1, 125, NC), 128, 0, stream>>>(A3, w4p, out, n0);
    }
}

// Round 11
// 187.461 us; speedup vs baseline: 19.6293x; 1.0175x over previous
//
#include <hip/hip_runtime.h>
#include <hip/hip_bf16.h>
#include <cstdint>

// ---------------------------------------------------------------------------
// Binarized CNN. Verified numerics (R5-R10 passed bit-exact):
//  - binarize(x) == sign(x) exactly; layers 2-4 are exact small-int math in
//    any order -> any packing / instruction choice is safe.
//  - conv1: each accumulator chain MUST sum in (ky,kx,ic)-ascending order
//    (Eigen/XLA-CPU im2col). Chains are independent -> interleaving ACROSS
//    chains (e.g. oc-outer) is bit-exact. DO NOT reorder WITHIN a chain.
//  - k2/k3: MFMA v_mfma_i32_32x32x32_i8 per-tap GEMM (R9, verified).
//  - R11: k1 oc-outermost (4 live accs instead of 32 -> no register
//    reload storm); kprep split across 3 blocks.
// ---------------------------------------------------------------------------

typedef __attribute__((ext_vector_type(4)))  int int4v;
typedef __attribute__((ext_vector_type(16))) int int16v;

#define WOFF_W2M 0          // int[9*64*4]  = 9216 B  (MFMA B-frag table L2)
#define WOFF_W3M 10240      // int[9*64*4]  = 9216 B  (MFMA B-frag table L3)
#define WOFF_W4P 20480      // int[2*8*9]   = 576 B   (dot4 packs L4)
#define WOFF_W1S 22528      // float[216]
#define WEIGHTS_BYTES 32768

#define A1_PB (2*256*256*4)     // bytes per batch (packed u32, 4 ch/dword)
#define A2_PB (4*254*254*4)
#define A3_PB (8*252*252*4)

__device__ __forceinline__ int dot4(int a, int b, int c) {
#if __has_builtin(__builtin_amdgcn_sdot4)
    return __builtin_amdgcn_sdot4(a, b, c, false);
#else
    int s = c;
#pragma unroll
    for (int j = 0; j < 4; ++j) {
        int av = (a << (24 - 8 * j)) >> 24;
        int bv = (b << (24 - 8 * j)) >> 24;
        s += av * bv;
    }
    return s;
#endif
}

__device__ __forceinline__ int fsign(float w) {
    return (w > 0.f) ? 1 : ((w < 0.f) ? -1 : 0);
}

// ---- weight prep: 3 blocks (one per table group) -------------------------
__global__ __launch_bounds__(256) void kprep(const float* __restrict__ w1,
                                             const float* __restrict__ w2,
                                             const float* __restrict__ w3,
                                             const float* __restrict__ w4,
                                             int* __restrict__ w2m,
                                             int* __restrict__ w3m,
                                             int* __restrict__ w4p,
                                             float* __restrict__ w1s) {
    int tid = threadIdx.x;
    int b = blockIdx.x;
    if (b == 0) {
        // MFMA B-frag table L2: lane l -> col oc=l&31, K bytes ic=(l>>5)*16+j
        for (int idx = tid; idx < 576; idx += 256) {
            int t = idx / 64, l = idx % 64;
            int oc = l & 31, icb = (l >> 5) * 16;
            int wd[4] = {0, 0, 0, 0};
            for (int j = 0; j < 16; ++j) {
                int ic = icb + j;
                int s = (oc < 16 && ic < 8) ? fsign(w2[(oc * 8 + ic) * 9 + t]) : 0;
                wd[j >> 2] |= (s & 0xff) << (8 * (j & 3));
            }
            w2m[idx * 4 + 0] = wd[0]; w2m[idx * 4 + 1] = wd[1];
            w2m[idx * 4 + 2] = wd[2]; w2m[idx * 4 + 3] = wd[3];
        }
    } else if (b == 1) {
        for (int idx = tid; idx < 576; idx += 256) {
            int t = idx / 64, l = idx % 64;
            int oc = l & 31, icb = (l >> 5) * 16;
            int wd[4] = {0, 0, 0, 0};
            for (int j = 0; j < 16; ++j) {
                int ic = icb + j;
                int s = (ic < 16) ? fsign(w3[(oc * 16 + ic) * 9 + t]) : 0;
                wd[j >> 2] |= (s & 0xff) << (8 * (j & 3));
            }
            w3m[idx * 4 + 0] = wd[0]; w3m[idx * 4 + 1] = wd[1];
            w3m[idx * 4 + 2] = wd[2]; w3m[idx * 4 + 3] = wd[3];
        }
    } else {
        for (int idx = tid; idx < 2 * 8 * 9; idx += 256) {
            int k = idx % 9, icg = (idx / 9) % 8, oc = idx / 72;
            int pack = 0;
#pragma unroll
            for (int j = 0; j < 4; ++j)
                pack |= (fsign(w4[(oc * 32 + icg * 4 + j) * 9 + k]) & 0xff) << (8 * j);
            w4p[idx] = pack;
        }
        for (int i = tid; i < 216; i += 256) {
            float w = w1[i];
            w1s[i] = (w > 0.f) ? 1.f : ((w < 0.f) ? -1.f : 0.f);
        }
    }
}

// ---- layer 1: pad(1)+conv(3->8)+hardtanh+maxpool2+sign, packed out -------
// R11: oc outermost -> only 4 accumulators live. Each chain still sums in
// strict (ky,kx,ic)-ascending order: BIT-EXACT vs the verified kernel.
__global__ __launch_bounds__(256, 4) void k1(const float* __restrict__ x,
                                             const float* __restrict__ w1s,
                                             uint32_t* __restrict__ a1, int n0) {
    int ox = threadIdx.x;   // 0..255
    int oy = blockIdx.y;    // 0..255
    int ln = blockIdx.z;
    const float* xn = x + (size_t)(n0 + ln) * 3 * 512 * 512;

    float v[3][16];
    int iy0 = 2 * oy - 1, ix0 = 2 * ox - 1;

    if (oy > 0 && oy < 255 && ox > 0 && ox < 255) {
        // interior: unguarded; middle two columns even-indexed -> float2
#pragma unroll
        for (int ic = 0; ic < 3; ++ic) {
            const float* xc = xn + (size_t)ic * 512 * 512;
#pragma unroll
            for (int r = 0; r < 4; ++r) {
                const float* rp = xc + (size_t)(iy0 + r) * 512 + ix0;
                v[ic][r * 4 + 0] = rp[0];
                float2 m = *(const float2*)(rp + 1);
                v[ic][r * 4 + 1] = m.x;
                v[ic][r * 4 + 2] = m.y;
                v[ic][r * 4 + 3] = rp[3];
            }
        }
    } else {
        // border: guarded path (pad value 1.0)
        for (int ic = 0; ic < 3; ++ic) {
            const float* xc = xn + (size_t)ic * 512 * 512;
#pragma unroll
            for (int r = 0; r < 4; ++r) {
                int iy = iy0 + r;
                bool yok = ((unsigned)iy < 512u);
#pragma unroll
                for (int c = 0; c < 4; ++c) {
                    int ix = ix0 + c;
                    v[ic][r * 4 + c] = (yok && ((unsigned)ix < 512u))
                                           ? xc[(size_t)iy * 512 + ix] : 1.0f;
                }
            }
        }
    }

    uint32_t d0 = 0, d1 = 0;
#pragma unroll
    for (int o = 0; o < 8; ++o) {
        float a0 = 0.f, a1v = 0.f, a2 = 0.f, a3 = 0.f;
#pragma unroll
        for (int ky = 0; ky < 3; ++ky) {
#pragma unroll
            for (int kx = 0; kx < 3; ++kx) {
#pragma unroll
                for (int ic = 0; ic < 3; ++ic) {
                    float w = w1s[o * 27 + ic * 9 + ky * 3 + kx];
                    a0 += w * v[ic][(ky + 0) * 4 + (kx + 0)];
                    a1v += w * v[ic][(ky + 0) * 4 + (kx + 1)];
                    a2 += w * v[ic][(ky + 1) * 4 + (kx + 0)];
                    a3 += w * v[ic][(ky + 1) * 4 + (kx + 1)];
                }
            }
        }
        float m = fmaxf(fmaxf(a0, a1v), fmaxf(a2, a3));
        int sg = (m > 0.f) ? 1 : ((m < 0.f) ? -1 : 0);
        if (o < 4) d0 |= (uint32_t)(sg & 0xff) << (8 * o);
        else       d1 |= (uint32_t)(sg & 0xff) << (8 * (o - 4));
    }
    size_t base = (((size_t)ln * 2) * 256 + oy) * 256 + ox;
    a1[base]             = d0;
    a1[base + 256 * 256] = d1;
}

// ---- layers 2/3: ternary conv via MFMA i32_32x32x32_i8 -------------------
template<int ICG, int INW, int OUTW, int OCGO>
__global__ __launch_bounds__(256) void kconv(const uint32_t* __restrict__ ain,
                                             const int* __restrict__ wm,
                                             uint32_t* __restrict__ aout) {
    __shared__ uint32_t st[4][3][36][4];   // [wave][row][x][icg] staged acts
    __shared__ uint32_t ep[4][32][9];      // [wave][x][ocg] epilogue repack
    int w    = threadIdx.x >> 6;
    int lane = threadIdx.x & 63;
    int x0 = blockIdx.x * 32;
    int y  = blockIdx.y * 4 + w;
    int ln = blockIdx.z;

    const int4v* wmv = (const int4v*)wm;
    int4v bfr[9];
#pragma unroll
    for (int t = 0; t < 9; ++t) bfr[t] = wmv[t * 64 + lane];

    const uint32_t* abase = ain + (size_t)ln * ICG * INW * INW;
    for (int idx = lane; idx < 432; idx += 64) {
        int icg = idx & 3, tmp = idx >> 2;
        int xx = tmp % 36, row = tmp / 36;
        int gy = y + row, gx = x0 + xx;
        uint32_t val = 0;
        if (icg < ICG && xx < 34 && gx < INW && gy < INW)
            val = abase[((size_t)icg * INW + gy) * INW + gx];
        st[w][row][xx][icg] = val;
    }

    int16v acc = {};
    int xl = lane & 31;
#pragma unroll
    for (int ky = 0; ky < 3; ++ky) {
#pragma unroll
        for (int kx = 0; kx < 3; ++kx) {
            int4v a = *(const int4v*)&st[w][ky][xl + kx][0];
            acc = __builtin_amdgcn_mfma_i32_32x32x32_i8(a, bfr[ky * 3 + kx], acc, 0, 0, 0);
        }
    }

    signed char* epb = (signed char*)&ep[w][0][0];
    int oc = lane & 31;
#pragma unroll
    for (int r = 0; r < 16; ++r) {
        int m = (r & 3) + 8 * (r >> 2) + 4 * (lane >> 5);
        int val = min(max(acc[r], -1), 1);
        epb[m * 36 + oc] = (signed char)val;
    }
    if (y < OUTW && x0 + xl < OUTW) {
#pragma unroll
        for (int it = 0; it < 4; ++it) {
            int ocg = (lane >> 5) * 4 + it;
            if (ocg < OCGO)
                aout[(((size_t)ln * OCGO + ocg) * OUTW + y) * OUTW + x0 + xl] =
                    ep[w][xl][ocg];
        }
    }
}

// ---- layer 4: conv(32->2) ternary, dot4, 2x2 outputs/thread, f32 out -----
__global__ __launch_bounds__(128) void k4(const uint32_t* __restrict__ a3,
                                          const int* __restrict__ w4p,
                                          float* __restrict__ out, int n0) {
    int ox = threadIdx.x; if (ox >= 125) return;
    int oy0 = blockIdx.y * 2;
    int ln = blockIdx.z;

    int acc[2][2][2] = {};
#pragma unroll
    for (int icg = 0; icg < 8; ++icg) {
        uint32_t r[4][4];
        const uint32_t* base = a3 + (((size_t)ln * 8 + icg) * 252 + oy0) * 252 + 2 * ox;
#pragma unroll
        for (int j = 0; j < 4; ++j) {
            uint2 lo = *(const uint2*)(base + (size_t)j * 252);
            uint2 hi = *(const uint2*)(base + (size_t)j * 252 + 2);
            r[j][0] = lo.x; r[j][1] = lo.y; r[j][2] = hi.x; r[j][3] = hi.y;
        }
#pragma unroll
        for (int o = 0; o < 2; ++o) {
            const int* wb = w4p + ((o * 8 + icg) * 9);
#pragma unroll
            for (int ky = 0; ky < 3; ++ky) {
#pragma unroll
                for (int p = 0; p < 2; ++p) {
#pragma unroll
                    for (int q = 0; q < 2; ++q) {
                        acc[p][q][o] = dot4((int)r[p + ky][q + 0], wb[ky * 3 + 0], acc[p][q][o]);
                        acc[p][q][o] = dot4((int)r[p + ky][q + 1], wb[ky * 3 + 1], acc[p][q][o]);
                        acc[p][q][o] = dot4((int)r[p + ky][q + 2], wb[ky * 3 + 2], acc[p][q][o]);
                    }
                }
            }
        }
    }
    size_t gn = (size_t)(n0 + ln);
#pragma unroll
    for (int o = 0; o < 2; ++o)
#pragma unroll
        for (int p = 0; p < 2; ++p) {
            float2 w;
            w.x = fminf(fmaxf((float)acc[p][0][o], -1.f), 1.f);
            w.y = fminf(fmaxf((float)acc[p][1][o], -1.f), 1.f);
            *(float2*)(out + ((gn * 2 + o) * 250 + (oy0 + p)) * 250 + 2 * ox) = w;
        }
}

extern "C" void kernel_launch(void* const* d_in, const int* in_sizes, int n_in,
                              void* d_out, int out_size, void* d_ws, size_t ws_size,
                              hipStream_t stream) {
    const float* x  = (const float*)d_in[0];
    const float* w1 = (const float*)d_in[1];
    const float* w2 = (const float*)d_in[2];
    const float* w3 = (const float*)d_in[3];
    const float* w4 = (const float*)d_in[4];
    char* ws = (char*)d_ws;

    int*   w2m = (int*)(ws + WOFF_W2M);
    int*   w3m = (int*)(ws + WOFF_W3M);
    int*   w4p = (int*)(ws + WOFF_W4P);
    float* w1s = (float*)(ws + WOFF_W1S);
    float* out = (float*)d_out;

    size_t per = (size_t)A1_PB + (size_t)A2_PB + (size_t)A3_PB;
    int NC = 32;
    while (NC > 1 && (size_t)WEIGHTS_BYTES + (size_t)NC * per > ws_size) NC >>= 1;

    uint32_t* A1 = (uint32_t*)(ws + WEIGHTS_BYTES);
    uint32_t* A2 = (uint32_t*)(ws + WEIGHTS_BYTES + (size_t)NC * A1_PB);
    uint32_t* A3 = (uint32_t*)(ws + WEIGHTS_BYTES + (size_t)NC * (A1_PB + A2_PB));

    kprep<<<dim3(3), 256, 0, stream>>>(w1, w2, w3, w4, w2m, w3m, w4p, w1s);
    for (int n0 = 0; n0 < 32; n0 += NC) {
        k1<<<dim3(1, 256, NC), 256, 0, stream>>>(x, w1s, A1, n0);
        kconv<2, 256, 254, 4><<<dim3(8, 64, NC), 256, 0, stream>>>(A1, w2m, A2);
        kconv<4, 254, 252, 8><<<dim3(8, 63, NC), 256, 0, stream>>>(A2, w3m, A3);
        k4<<<dim3(1, 125, NC), 128, 0, stream>>>(A3, w4p, out, n0);
    }
}

// Round 12
// 176.187 us; speedup vs baseline: 20.8853x; 1.0640x over previous
//
#include <hip/hip_runtime.h>
#include <hip/hip_bf16.h>
#include <cstdint>

// ---------------------------------------------------------------------------
// Binarized CNN. Verified numerics (R5-R11 passed bit-exact):
//  - binarize(x) == sign(x) exactly; layers 2-4 are exact small-int math in
//    any order -> any packing / instruction choice is safe.
//  - conv1: each accumulator chain MUST sum in (ky,kx,ic)-ascending order
//    (Eigen/XLA-CPU im2col). Chains are independent; fma == mul+add here
//    (weights are +-1/0 so products are exact). DO NOT reorder WITHIN a chain.
//  - k2/k3: MFMA v_mfma_i32_32x32x32_i8 per-tap GEMM (R9, verified).
//  - R12: k1 uses explicit v_pk_fma_f32 (2 chains per issue): acc01 packs
//    the two horizontal pool positions, acc23 the lower two. Window held as
//    overlapping horizontal f32x2 pairs; weights prepacked {w,w} -> SGPR pair.
// ---------------------------------------------------------------------------

typedef __attribute__((ext_vector_type(2)))  float f32x2;
typedef __attribute__((ext_vector_type(4)))  int int4v;
typedef __attribute__((ext_vector_type(16))) int int16v;

#define WOFF_W2M 0          // int[9*64*4]  = 9216 B  (MFMA B-frag table L2)
#define WOFF_W3M 10240      // int[9*64*4]  = 9216 B  (MFMA B-frag table L3)
#define WOFF_W4P 20480      // int[2*8*9]   = 576 B   (dot4 packs L4)
#define WOFF_W1D 22528      // f32x2[216]   = 1728 B  ({w,w} pairs for k1)
#define WEIGHTS_BYTES 32768

#define A1_PB (2*256*256*4)     // bytes per batch (packed u32, 4 ch/dword)
#define A2_PB (4*254*254*4)
#define A3_PB (8*252*252*4)

__device__ __forceinline__ int dot4(int a, int b, int c) {
#if __has_builtin(__builtin_amdgcn_sdot4)
    return __builtin_amdgcn_sdot4(a, b, c, false);
#else
    int s = c;
#pragma unroll
    for (int j = 0; j < 4; ++j) {
        int av = (a << (24 - 8 * j)) >> 24;
        int bv = (b << (24 - 8 * j)) >> 24;
        s += av * bv;
    }
    return s;
#endif
}

__device__ __forceinline__ int fsign(float w) {
    return (w > 0.f) ? 1 : ((w < 0.f) ? -1 : 0);
}

// ---- weight prep: 3 blocks (one per table group) -------------------------
__global__ __launch_bounds__(256) void kprep(const float* __restrict__ w1,
                                             const float* __restrict__ w2,
                                             const float* __restrict__ w3,
                                             const float* __restrict__ w4,
                                             int* __restrict__ w2m,
                                             int* __restrict__ w3m,
                                             int* __restrict__ w4p,
                                             f32x2* __restrict__ w1d) {
    int tid = threadIdx.x;
    int b = blockIdx.x;
    if (b == 0) {
        for (int idx = tid; idx < 576; idx += 256) {
            int t = idx / 64, l = idx % 64;
            int oc = l & 31, icb = (l >> 5) * 16;
            int wd[4] = {0, 0, 0, 0};
            for (int j = 0; j < 16; ++j) {
                int ic = icb + j;
                int s = (oc < 16 && ic < 8) ? fsign(w2[(oc * 8 + ic) * 9 + t]) : 0;
                wd[j >> 2] |= (s & 0xff) << (8 * (j & 3));
            }
            w2m[idx * 4 + 0] = wd[0]; w2m[idx * 4 + 1] = wd[1];
            w2m[idx * 4 + 2] = wd[2]; w2m[idx * 4 + 3] = wd[3];
        }
    } else if (b == 1) {
        for (int idx = tid; idx < 576; idx += 256) {
            int t = idx / 64, l = idx % 64;
            int oc = l & 31, icb = (l >> 5) * 16;
            int wd[4] = {0, 0, 0, 0};
            for (int j = 0; j < 16; ++j) {
                int ic = icb + j;
                int s = (ic < 16) ? fsign(w3[(oc * 16 + ic) * 9 + t]) : 0;
                wd[j >> 2] |= (s & 0xff) << (8 * (j & 3));
            }
            w3m[idx * 4 + 0] = wd[0]; w3m[idx * 4 + 1] = wd[1];
            w3m[idx * 4 + 2] = wd[2]; w3m[idx * 4 + 3] = wd[3];
        }
    } else {
        for (int idx = tid; idx < 2 * 8 * 9; idx += 256) {
            int k = idx % 9, icg = (idx / 9) % 8, oc = idx / 72;
            int pack = 0;
#pragma unroll
            for (int j = 0; j < 4; ++j)
                pack |= (fsign(w4[(oc * 32 + icg * 4 + j) * 9 + k]) & 0xff) << (8 * j);
            w4p[idx] = pack;
        }
        for (int i = tid; i < 216; i += 256) {
            float w = w1[i];
            float s = (w > 0.f) ? 1.f : ((w < 0.f) ? -1.f : 0.f);
            w1d[i] = (f32x2){s, s};
        }
    }
}

// ---- layer 1: pad(1)+conv(3->8)+hardtanh+maxpool2+sign, packed out -------
// R12: v_pk_fma_f32 — acc01 = chains for pool positions (0,0),(0,1);
// acc23 = (1,0),(1,1). Each half's chain is strict (ky,kx,ic)-ascending:
// BIT-EXACT vs the verified kernel (w in {+-1,0} -> products exact).
__global__ __launch_bounds__(256, 4) void k1(const float* __restrict__ x,
                                             const f32x2* __restrict__ w1d,
                                             uint32_t* __restrict__ a1, int n0) {
    int ox = threadIdx.x;   // 0..255
    int oy = blockIdx.y;    // 0..255
    int ln = blockIdx.z;
    const float* xn = x + (size_t)(n0 + ln) * 3 * 512 * 512;

    // window as overlapping horizontal pairs: hp[ic][r][c] = {v[r][c], v[r][c+1]}
    f32x2 hp[3][4][3];
    int iy0 = 2 * oy - 1, ix0 = 2 * ox - 1;

    if (oy > 0 && oy < 255 && ox > 0 && ox < 255) {
#pragma unroll
        for (int ic = 0; ic < 3; ++ic) {
            const float* xc = xn + (size_t)ic * 512 * 512;
#pragma unroll
            for (int r = 0; r < 4; ++r) {
                const float* rp = xc + (size_t)(iy0 + r) * 512 + ix0;
                float a = rp[0];
                float2 m = *(const float2*)(rp + 1);
                float b = rp[3];
                hp[ic][r][0] = (f32x2){a, m.x};
                hp[ic][r][1] = (f32x2){m.x, m.y};
                hp[ic][r][2] = (f32x2){m.y, b};
            }
        }
    } else {
        for (int ic = 0; ic < 3; ++ic) {
            const float* xc = xn + (size_t)ic * 512 * 512;
#pragma unroll
            for (int r = 0; r < 4; ++r) {
                int iy = iy0 + r;
                bool yok = ((unsigned)iy < 512u);
                float t[4];
#pragma unroll
                for (int c = 0; c < 4; ++c) {
                    int ix = ix0 + c;
                    t[c] = (yok && ((unsigned)ix < 512u))
                               ? xc[(size_t)iy * 512 + ix] : 1.0f;
                }
                hp[ic][r][0] = (f32x2){t[0], t[1]};
                hp[ic][r][1] = (f32x2){t[1], t[2]};
                hp[ic][r][2] = (f32x2){t[2], t[3]};
            }
        }
    }

    uint64_t dall = 0;
#pragma unroll 1
    for (int o = 0; o < 8; ++o) {
        f32x2 acc01 = {0.f, 0.f}, acc23 = {0.f, 0.f};
        const f32x2* wb = w1d + o * 27;
#pragma unroll
        for (int ky = 0; ky < 3; ++ky) {
#pragma unroll
            for (int kx = 0; kx < 3; ++kx) {
#pragma unroll
                for (int ic = 0; ic < 3; ++ic) {
                    f32x2 ww = wb[ic * 9 + ky * 3 + kx];   // uniform {w,w}
                    asm("v_pk_fma_f32 %0, %1, %2, %0"
                        : "+v"(acc01) : "s"(ww), "v"(hp[ic][ky][kx]));
                    asm("v_pk_fma_f32 %0, %1, %2, %0"
                        : "+v"(acc23) : "s"(ww), "v"(hp[ic][ky + 1][kx]));
                }
            }
        }
        float m = fmaxf(fmaxf(acc01[0], acc01[1]), fmaxf(acc23[0], acc23[1]));
        int sg = (m > 0.f) ? 1 : ((m < 0.f) ? -1 : 0);
        dall |= (uint64_t)(uint32_t)(sg & 0xff) << (8 * o);
    }
    uint32_t d0 = (uint32_t)dall;
    uint32_t d1 = (uint32_t)(dall >> 32);
    size_t base = (((size_t)ln * 2) * 256 + oy) * 256 + ox;
    a1[base]             = d0;
    a1[base + 256 * 256] = d1;
}

// ---- layers 2/3: ternary conv via MFMA i32_32x32x32_i8 -------------------
template<int ICG, int INW, int OUTW, int OCGO>
__global__ __launch_bounds__(256) void kconv(const uint32_t* __restrict__ ain,
                                             const int* __restrict__ wm,
                                             uint32_t* __restrict__ aout) {
    __shared__ uint32_t st[4][3][36][4];   // [wave][row][x][icg] staged acts
    __shared__ uint32_t ep[4][32][9];      // [wave][x][ocg] epilogue repack
    int w    = threadIdx.x >> 6;
    int lane = threadIdx.x & 63;
    int x0 = blockIdx.x * 32;
    int y  = blockIdx.y * 4 + w;
    int ln = blockIdx.z;

    const int4v* wmv = (const int4v*)wm;
    int4v bfr[9];
#pragma unroll
    for (int t = 0; t < 9; ++t) bfr[t] = wmv[t * 64 + lane];

    const uint32_t* abase = ain + (size_t)ln * ICG * INW * INW;
    for (int idx = lane; idx < 432; idx += 64) {
        int icg = idx & 3, tmp = idx >> 2;
        int xx = tmp % 36, row = tmp / 36;
        int gy = y + row, gx = x0 + xx;
        uint32_t val = 0;
        if (icg < ICG && xx < 34 && gx < INW && gy < INW)
            val = abase[((size_t)icg * INW + gy) * INW + gx];
        st[w][row][xx][icg] = val;
    }

    int16v acc = {};
    int xl = lane & 31;
#pragma unroll
    for (int ky = 0; ky < 3; ++ky) {
#pragma unroll
        for (int kx = 0; kx < 3; ++kx) {
            int4v a = *(const int4v*)&st[w][ky][xl + kx][0];
            acc = __builtin_amdgcn_mfma_i32_32x32x32_i8(a, bfr[ky * 3 + kx], acc, 0, 0, 0);
        }
    }

    signed char* epb = (signed char*)&ep[w][0][0];
    int oc = lane & 31;
#pragma unroll
    for (int r = 0; r < 16; ++r) {
        int m = (r & 3) + 8 * (r >> 2) + 4 * (lane >> 5);
        int val = min(max(acc[r], -1), 1);
        epb[m * 36 + oc] = (signed char)val;
    }
    if (y < OUTW && x0 + xl < OUTW) {
#pragma unroll
        for (int it = 0; it < 4; ++it) {
            int ocg = (lane >> 5) * 4 + it;
            if (ocg < OCGO)
                aout[(((size_t)ln * OCGO + ocg) * OUTW + y) * OUTW + x0 + xl] =
                    ep[w][xl][ocg];
        }
    }
}

// ---- layer 4: conv(32->2) ternary, dot4, 2x2 outputs/thread, f32 out -----
__global__ __launch_bounds__(128) void k4(const uint32_t* __restrict__ a3,
                                          const int* __restrict__ w4p,
                                          float* __restrict__ out, int n0) {
    int ox = threadIdx.x; if (ox >= 125) return;
    int oy0 = blockIdx.y * 2;
    int ln = blockIdx.z;

    int acc[2][2][2] = {};
#pragma unroll
    for (int icg = 0; icg < 8; ++icg) {
        uint32_t r[4][4];
        const uint32_t* base = a3 + (((size_t)ln * 8 + icg) * 252 + oy0) * 252 + 2 * ox;
#pragma unroll
        for (int j = 0; j < 4; ++j) {
            uint2 lo = *(const uint2*)(base + (size_t)j * 252);
            uint2 hi = *(const uint2*)(base + (size_t)j * 252 + 2);
            r[j][0] = lo.x; r[j][1] = lo.y; r[j][2] = hi.x; r[j][3] = hi.y;
        }
#pragma unroll
        for (int o = 0; o < 2; ++o) {
            const int* wb = w4p + ((o * 8 + icg) * 9);
#pragma unroll
            for (int ky = 0; ky < 3; ++ky) {
#pragma unroll
                for (int p = 0; p < 2; ++p) {
#pragma unroll
                    for (int q = 0; q < 2; ++q) {
                        acc[p][q][o] = dot4((int)r[p + ky][q + 0], wb[ky * 3 + 0], acc[p][q][o]);
                        acc[p][q][o] = dot4((int)r[p + ky][q + 1], wb[ky * 3 + 1], acc[p][q][o]);
                        acc[p][q][o] = dot4((int)r[p + ky][q + 2], wb[ky * 3 + 2], acc[p][q][o]);
                    }
                }
            }
        }
    }
    size_t gn = (size_t)(n0 + ln);
#pragma unroll
    for (int o = 0; o < 2; ++o)
#pragma unroll
        for (int p = 0; p < 2; ++p) {
            float2 w;
            w.x = fminf(fmaxf((float)acc[p][0][o], -1.f), 1.f);
            w.y = fminf(fmaxf((float)acc[p][1][o], -1.f), 1.f);
            *(float2*)(out + ((gn * 2 + o) * 250 + (oy0 + p)) * 250 + 2 * ox) = w;
        }
}

extern "C" void kernel_launch(void* const* d_in, const int* in_sizes, int n_in,
                              void* d_out, int out_size, void* d_ws, size_t ws_size,
                              hipStream_t stream) {
    const float* x  = (const float*)d_in[0];
    const float* w1 = (const float*)d_in[1];
    const float* w2 = (const float*)d_in[2];
    const float* w3 = (const float*)d_in[3];
    const float* w4 = (const float*)d_in[4];
    char* ws = (char*)d_ws;

    int*   w2m = (int*)(ws + WOFF_W2M);
    int*   w3m = (int*)(ws + WOFF_W3M);
    int*   w4p = (int*)(ws + WOFF_W4P);
    f32x2* w1d = (f32x2*)(ws + WOFF_W1D);
    float* out = (float*)d_out;

    size_t per = (size_t)A1_PB + (size_t)A2_PB + (size_t)A3_PB;
    int NC = 32;
    while (NC > 1 && (size_t)WEIGHTS_BYTES + (size_t)NC * per > ws_size) NC >>= 1;

    uint32_t* A1 = (uint32_t*)(ws + WEIGHTS_BYTES);
    uint32_t* A2 = (uint32_t*)(ws + WEIGHTS_BYTES + (size_t)NC * A1_PB);
    uint32_t* A3 = (uint32_t*)(ws + WEIGHTS_BYTES + (size_t)NC * (A1_PB + A2_PB));

    kprep<<<dim3(3), 256, 0, stream>>>(w1, w2, w3, w4, w2m, w3m, w4p, w1d);
    for (int n0 = 0; n0 < 32; n0 += NC) {
        k1<<<dim3(1, 256, NC), 256, 0, stream>>>(x, w1d, A1, n0);
        kconv<2, 256, 254, 4><<<dim3(8, 64, NC), 256, 0, stream>>>(A1, w2m, A2);
        kconv<4, 254, 252, 8><<<dim3(8, 63, NC), 256, 0, stream>>>(A2, w3m, A3);
        k4<<<dim3(1, 125, NC), 128, 0, stream>>>(A3, w4p, out, n0);
    }
}